// Round 2
// baseline (3809.163 us; speedup 1.0000x reference)
//
#include <hip/hip_runtime.h>
#include <hip/hip_fp16.h>

#define TDIM 512
#define FDIM 80

// ---------------- conv 3x3, 64->64, in NHWC [B,T,F,64] fp32, out [B,C,T,F] fp16 ----------------
__global__ __launch_bounds__(256) void k_conv_in(
    const float* __restrict__ x, const float* __restrict__ w,
    const float* __restrict__ bias, __half* __restrict__ y)
{
  __shared__ float tile[246 * 64];   // rows: ky*82 + (f+1), stride 64 (ci)
  const int bid = blockIdx.x;
  const int b = bid >> 9, t = bid & 511;
  const int tid = threadIdx.x;

  // stage input rows t-1..t+1, f -1..80 (zero-padded), float4 over ci
  for (int idx = tid; idx < 246 * 16; idx += 256) {
    int row = idx >> 4, cq = idx & 15;
    int ky = row / 82, fi = row - ky * 82;
    int tt = t + ky - 1, ff = fi - 1;
    float4 v = make_float4(0.f, 0.f, 0.f, 0.f);
    if (tt >= 0 && tt < TDIM && ff >= 0 && ff < FDIM)
      v = *reinterpret_cast<const float4*>(x + (((b * TDIM + tt) * FDIM + ff) << 6) + cq * 4);
    *reinterpret_cast<float4*>(tile + (row << 6) + cq * 4) = v;
  }
  __syncthreads();

  const int cg = tid & 15, fg = tid >> 4;
  const int c0 = cg * 4, f0 = fg * 5;
  float acc[4][5];
  #pragma unroll
  for (int i = 0; i < 4; i++) {
    float bv = bias[c0 + i];
    #pragma unroll
    for (int j = 0; j < 5; j++) acc[i][j] = bv;
  }

  for (int ky = 0; ky < 3; ky++) {
    for (int ciq = 0; ciq < 16; ciq++) {
      const float* tp = tile + ((ky * 82 + f0) << 6) + ciq * 4;
      float4 iv[7];
      #pragma unroll
      for (int d = 0; d < 7; d++) iv[d] = *reinterpret_cast<const float4*>(tp + (d << 6));
      #pragma unroll
      for (int kx = 0; kx < 3; kx++) {
        const float* wp = w + (((ky * 3 + kx) * 64 + ciq * 4) << 6) + c0;
        float4 w0 = *reinterpret_cast<const float4*>(wp);
        float4 w1 = *reinterpret_cast<const float4*>(wp + 64);
        float4 w2 = *reinterpret_cast<const float4*>(wp + 128);
        float4 w3 = *reinterpret_cast<const float4*>(wp + 192);
        #pragma unroll
        for (int ff = 0; ff < 5; ff++) {
          float4 v = iv[ff + kx];
          acc[0][ff] += v.x * w0.x + v.y * w1.x + v.z * w2.x + v.w * w3.x;
          acc[1][ff] += v.x * w0.y + v.y * w1.y + v.z * w2.y + v.w * w3.y;
          acc[2][ff] += v.x * w0.z + v.y * w1.z + v.z * w2.z + v.w * w3.z;
          acc[3][ff] += v.x * w0.w + v.y * w1.w + v.z * w2.w + v.w * w3.w;
        }
      }
    }
  }
  __syncthreads();                   // done reading input tile
  float* yt = tile;                  // overlay: [64][81]
  #pragma unroll
  for (int i = 0; i < 4; i++)
    #pragma unroll
    for (int j = 0; j < 5; j++)
      yt[(c0 + i) * 81 + f0 + j] = acc[i][j];
  __syncthreads();
  // coalesced-ish write to [B,C,T,F] fp16
  for (int it = 0; it < 20; it++) {
    int idx = tid + (it << 8);       // 0..5119
    int c = idx / 80, f = idx - c * 80;
    y[((b * 64 + c) * TDIM + t) * FDIM + f] = __float2half(yt[c * 81 + f]);
  }
}

// ---------------- freq attention: per (b,c), L=T=512, D=F=80, flash over m ----------------
__global__ __launch_bounds__(256) void k_attn_freq(
    const __half* __restrict__ XQ, const __half* __restrict__ XK,
    const __half* __restrict__ XV, __half* __restrict__ CAT)
{
  __shared__ float Qs[32 * 100];     // [r][f] f padded to 96(+4), stride 100
  __shared__ float Ks[32 * 100];
  __shared__ float Vs[32 * 100];
  __shared__ float Ss[32 * 36];      // [r][m] stride 36
  const int bid = blockIdx.x;
  const int bc = bid & 511, tl = bid >> 9;   // same-(b,c) tiles share XCD (512 % 8 == 0)
  const int t0 = tl * 32;
  const int b = bc >> 6, c = bc & 63;
  const int tid = threadIdx.x;
  const float qscale = 0.1118033988749895f;  // 1/sqrt(80)

  const __half* Qp = XQ + bc * 40960 + t0 * 80;
  for (int idx = tid; idx < 32 * 24; idx += 256) {
    int r = idx / 24, f4 = idx - r * 24;
    float4 v = make_float4(0.f, 0.f, 0.f, 0.f);
    if (f4 < 20) {
      const __half2* hp = reinterpret_cast<const __half2*>(Qp + r * 80 + f4 * 4);
      float2 a = __half22float2(hp[0]), bb = __half22float2(hp[1]);
      v = make_float4(a.x * qscale, a.y * qscale, bb.x * qscale, bb.y * qscale);
    }
    *reinterpret_cast<float4*>(Qs + r * 100 + f4 * 4) = v;
  }

  const int r = tid >> 3, fl = tid & 7;
  float O[12];
  #pragma unroll
  for (int j = 0; j < 12; j++) O[j] = 0.f;
  float m_r = -1e30f, l_r = 0.f;

  for (int mt = 0; mt < 16; mt++) {
    __syncthreads();                 // prev phase-C reads of Ks/Vs complete
    const __half* Kp = XK + bc * 40960 + mt * 32 * 80;
    const __half* Vp = XV + bc * 40960 + mt * 32 * 80;
    for (int idx = tid; idx < 32 * 24; idx += 256) {
      int rr = idx / 24, f4 = idx - rr * 24;
      float4 kv = make_float4(0.f, 0.f, 0.f, 0.f), vv = kv;
      if (f4 < 20) {
        const __half2* kp = reinterpret_cast<const __half2*>(Kp + rr * 80 + f4 * 4);
        const __half2* vp = reinterpret_cast<const __half2*>(Vp + rr * 80 + f4 * 4);
        float2 ka = __half22float2(kp[0]), kb = __half22float2(kp[1]);
        float2 va = __half22float2(vp[0]), vb = __half22float2(vp[1]);
        kv = make_float4(ka.x, ka.y, kb.x, kb.y);
        vv = make_float4(va.x, va.y, vb.x, vb.y);
      }
      *reinterpret_cast<float4*>(Ks + rr * 100 + f4 * 4) = kv;
      *reinterpret_cast<float4*>(Vs + rr * 100 + f4 * 4) = vv;
    }
    __syncthreads();

    // phase A: scores S[r][m], m = fl + 8q
    float a[4][4];
    #pragma unroll
    for (int qq = 0; qq < 4; qq++)
      #pragma unroll
      for (int i = 0; i < 4; i++) a[qq][i] = 0.f;
    for (int f4 = 0; f4 < 24; f4++) {
      float4 qv = *reinterpret_cast<const float4*>(Qs + r * 100 + f4 * 4);
      #pragma unroll
      for (int qq = 0; qq < 4; qq++) {
        float4 kv = *reinterpret_cast<const float4*>(Ks + (fl + 8 * qq) * 100 + f4 * 4);
        a[qq][0] += qv.x * kv.x; a[qq][1] += qv.y * kv.y;
        a[qq][2] += qv.z * kv.z; a[qq][3] += qv.w * kv.w;
      }
    }
    #pragma unroll
    for (int qq = 0; qq < 4; qq++)
      Ss[r * 36 + fl + 8 * qq] = (a[qq][0] + a[qq][1]) + (a[qq][2] + a[qq][3]);

    // phase B: online softmax update (own values + 8-lane shuffle reduce)
    float tm = -1e30f;
    #pragma unroll
    for (int qq = 0; qq < 4; qq++) tm = fmaxf(tm, Ss[r * 36 + fl + 8 * qq]);
    #pragma unroll
    for (int s = 1; s < 8; s <<= 1) tm = fmaxf(tm, __shfl_xor(tm, s, 8));
    float mnew = fmaxf(m_r, tm);
    float corr = __expf(m_r - mnew);
    float ls = 0.f;
    #pragma unroll
    for (int qq = 0; qq < 4; qq++) {
      float p = __expf(Ss[r * 36 + fl + 8 * qq] - mnew);
      Ss[r * 36 + fl + 8 * qq] = p;
      ls += p;
    }
    #pragma unroll
    for (int s = 1; s < 8; s <<= 1) ls += __shfl_xor(ls, s, 8);
    l_r = l_r * corr + ls;
    m_r = mnew;
    #pragma unroll
    for (int j = 0; j < 12; j++) O[j] *= corr;
    __syncthreads();                 // P values visible to whole row group

    // phase C: O[f] += sum_m P[r][m] * V[m][f], f = fl*12 + j
    for (int m = 0; m < 32; m++) {
      float p = Ss[r * 36 + m];
      const float* vp = Vs + m * 100 + fl * 12;
      float4 v0 = *reinterpret_cast<const float4*>(vp);
      float4 v1 = *reinterpret_cast<const float4*>(vp + 4);
      float4 v2 = *reinterpret_cast<const float4*>(vp + 8);
      O[0] += p * v0.x; O[1] += p * v0.y; O[2]  += p * v0.z; O[3]  += p * v0.w;
      O[4] += p * v1.x; O[5] += p * v1.y; O[6]  += p * v1.z; O[7]  += p * v1.w;
      O[8] += p * v2.x; O[9] += p * v2.y; O[10] += p * v2.z; O[11] += p * v2.w;
    }
  }

  float inv = 1.f / l_r;
  int base = ((b * TDIM + t0 + r) * FDIM) * 128 + 64 + c;   // freq -> channels 64..127
  #pragma unroll
  for (int j = 0; j < 12; j++) {
    int f = fl * 12 + j;
    if (f < 80) CAT[base + f * 128] = __float2half(O[j] * inv);
  }
}

// ---------------- time attention: per (b,c), L=F=80, D=T=512 ----------------
__global__ __launch_bounds__(256) void k_attn_time(
    const __half* __restrict__ XQ, const __half* __restrict__ XK,
    const __half* __restrict__ XV, __half* __restrict__ CAT)
{
  __shared__ float Qc[64 * 20];      // [t][fi] 16 f-cols, stride 20
  __shared__ float Kc[64 * 84];      // [t][g] stride 84 (also reused for V)
  __shared__ float Sp[16 * 84];      // [fi][g]
  const int bid = blockIdx.x;
  const int bc = bid & 511, fb = bid >> 9;
  const int b = bc >> 6, c = bc & 63;
  const int f0 = fb * 16;
  const int tid = threadIdx.x;
  const float tscale = 0.04419417382415922f; // 1/sqrt(512)
  const int fy = tid >> 4, gx = tid & 15;
  const __half* Qp = XQ + bc * 40960;
  const __half* Kp = XK + bc * 40960;
  const __half* Vp = XV + bc * 40960;

  float acc[5] = {0.f, 0.f, 0.f, 0.f, 0.f};
  for (int tc = 0; tc < 8; tc++) {
    __syncthreads();
    for (int idx = tid; idx < 64 * 16; idx += 256) {
      int t = idx >> 4, fi = idx & 15;
      Qc[t * 20 + fi] = __half2float(Qp[(tc * 64 + t) * 80 + f0 + fi]);
    }
    for (int idx = tid; idx < 64 * 80; idx += 256) {
      int t = idx / 80, g = idx - t * 80;
      Kc[t * 84 + g] = __half2float(Kp[(tc * 64 + t) * 80 + g]);
    }
    __syncthreads();
    for (int t = 0; t < 64; t++) {
      float qv = Qc[t * 20 + fy];
      #pragma unroll
      for (int i = 0; i < 5; i++) acc[i] += qv * Kc[t * 84 + gx * 5 + i];
    }
  }
  #pragma unroll
  for (int i = 0; i < 5; i++) Sp[fy * 84 + gx * 5 + i] = acc[i] * tscale;
  __syncthreads();

  // softmax over g (row fy, 16 lanes/row)
  float mx = -1e30f;
  float pv[5];
  #pragma unroll
  for (int j = 0; j < 5; j++) mx = fmaxf(mx, Sp[fy * 84 + gx + 16 * j]);
  #pragma unroll
  for (int s = 1; s < 16; s <<= 1) mx = fmaxf(mx, __shfl_xor(mx, s, 16));
  float ls = 0.f;
  #pragma unroll
  for (int j = 0; j < 5; j++) { pv[j] = __expf(Sp[fy * 84 + gx + 16 * j] - mx); ls += pv[j]; }
  #pragma unroll
  for (int s = 1; s < 16; s <<= 1) ls += __shfl_xor(ls, s, 16);
  float inv = 1.f / ls;
  __syncthreads();                   // all Sp reads done before overwrite
  #pragma unroll
  for (int j = 0; j < 5; j++) Sp[fy * 84 + gx + 16 * j] = pv[j] * inv;

  // PV: out'[f,t] = sum_g P[f,g] * V[t,g]; write transposed into CAT channels 0..63
  for (int tc = 0; tc < 8; tc++) {
    __syncthreads();
    for (int idx = tid; idx < 64 * 80; idx += 256) {
      int t = idx / 80, g = idx - t * 80;
      Kc[t * 84 + g] = __half2float(Vp[(tc * 64 + t) * 80 + g]);
    }
    __syncthreads();
    float o[4] = {0.f, 0.f, 0.f, 0.f};
    for (int g = 0; g < 80; g++) {
      float p = Sp[fy * 84 + g];
      #pragma unroll
      for (int j = 0; j < 4; j++) o[j] += p * Kc[(gx + 16 * j) * 84 + g];
    }
    #pragma unroll
    for (int j = 0; j < 4; j++) {
      int t = tc * 64 + gx + 16 * j;
      CAT[((b * TDIM + t) * FDIM + f0 + fy) * 128 + c] = __float2half(o[j]);
    }
  }
}

// ---------------- conv 3x3, 128->64, in [B,T,F,128] fp16 (CAT), out NHWC [B,T,F,64] fp32 ----------------
__global__ __launch_bounds__(256) void k_conv_out(
    const __half* __restrict__ x, const float* __restrict__ w,
    const float* __restrict__ bias, float* __restrict__ out)
{
  __shared__ float tile[126 * 64];   // rows: ky*42 + fi, 64-ch half, stride 64
  const int bid = blockIdx.x;
  const int b = bid >> 10, rem = bid & 1023;
  const int t = rem >> 1, fb = rem & 1;
  const int fbase = fb * 40;
  const int tid = threadIdx.x;
  const int cg = tid & 31, fg = tid >> 5;
  const int c0 = cg * 2, f0 = fg * 5;

  float acc[2][5];
  #pragma unroll
  for (int i = 0; i < 2; i++) {
    float bv = bias[c0 + i];
    #pragma unroll
    for (int j = 0; j < 5; j++) acc[i][j] = bv;
  }

  for (int hh = 0; hh < 2; hh++) {
    __syncthreads();                 // prior half's reads complete
    for (int idx = tid; idx < 126 * 16; idx += 256) {
      int row = idx >> 4, cq = idx & 15;
      int ky = row / 42, fi = row - ky * 42;
      int tt = t + ky - 1, ff = fbase + fi - 1;
      float4 v = make_float4(0.f, 0.f, 0.f, 0.f);
      if (tt >= 0 && tt < TDIM && ff >= 0 && ff < FDIM) {
        const __half2* hp = reinterpret_cast<const __half2*>(
            x + (((b * TDIM + tt) * FDIM + ff) << 7) + (hh << 6) + cq * 4);
        float2 a = __half22float2(hp[0]), bb = __half22float2(hp[1]);
        v = make_float4(a.x, a.y, bb.x, bb.y);
      }
      *reinterpret_cast<float4*>(tile + (row << 6) + cq * 4) = v;
    }
    __syncthreads();
    for (int ky = 0; ky < 3; ky++) {
      for (int ciq = 0; ciq < 16; ciq++) {
        const float* tp = tile + ((ky * 42 + f0) << 6) + ciq * 4;
        float4 iv[7];
        #pragma unroll
        for (int d = 0; d < 7; d++) iv[d] = *reinterpret_cast<const float4*>(tp + (d << 6));
        #pragma unroll
        for (int kx = 0; kx < 3; kx++) {
          const float* wp = w + (((ky * 3 + kx) * 128 + (hh << 6) + ciq * 4) << 6) + c0;
          float2 w0 = *reinterpret_cast<const float2*>(wp);
          float2 w1 = *reinterpret_cast<const float2*>(wp + 64);
          float2 w2 = *reinterpret_cast<const float2*>(wp + 128);
          float2 w3 = *reinterpret_cast<const float2*>(wp + 192);
          #pragma unroll
          for (int ff = 0; ff < 5; ff++) {
            float4 v = iv[ff + kx];
            acc[0][ff] += v.x * w0.x + v.y * w1.x + v.z * w2.x + v.w * w3.x;
            acc[1][ff] += v.x * w0.y + v.y * w1.y + v.z * w2.y + v.w * w3.y;
          }
        }
      }
    }
  }
  #pragma unroll
  for (int ff = 0; ff < 5; ff++) {
    int f = fbase + f0 + ff;
    float2 o;
    o.x = acc[0][ff]; o.y = acc[1][ff];
    *reinterpret_cast<float2*>(out + (((b * TDIM + t) * FDIM + f) << 6) + c0) = o;
  }
}

extern "C" void kernel_launch(void* const* d_in, const int* in_sizes, int n_in,
                              void* d_out, int out_size, void* d_ws, size_t ws_size,
                              hipStream_t stream)
{
  const float* q  = (const float*)d_in[0];
  const float* k  = (const float*)d_in[1];
  const float* v  = (const float*)d_in[2];
  const float* wq = (const float*)d_in[3];
  const float* bq = (const float*)d_in[4];
  const float* wk = (const float*)d_in[5];
  const float* bk = (const float*)d_in[6];
  const float* wv = (const float*)d_in[7];
  const float* bv = (const float*)d_in[8];
  const float* wo = (const float*)d_in[9];
  const float* bo = (const float*)d_in[10];

  const size_t PLANE = (size_t)8 * 64 * 512 * 80;   // 20,971,520 elements
  __half* XQh  = (__half*)d_ws;                     // PLANE halves
  __half* XKh  = XQh + PLANE;                       // PLANE halves
  __half* CATh = XKh + PLANE;                       // 2*PLANE halves  [B,T,F,128]
  __half* XVh  = (__half*)d_out;                    // PLANE halves (d_out = 2*PLANE half-slots); dead before k_conv_out writes

  hipLaunchKernelGGL(k_conv_in, dim3(4096), dim3(256), 0, stream, q, wq, bq, XQh);
  hipLaunchKernelGGL(k_conv_in, dim3(4096), dim3(256), 0, stream, k, wk, bk, XKh);
  hipLaunchKernelGGL(k_conv_in, dim3(4096), dim3(256), 0, stream, v, wv, bv, XVh);
  hipLaunchKernelGGL(k_attn_freq, dim3(8192), dim3(256), 0, stream, XQh, XKh, XVh, CATh);
  hipLaunchKernelGGL(k_attn_time, dim3(2560), dim3(256), 0, stream, XQh, XKh, XVh, CATh);
  hipLaunchKernelGGL(k_conv_out, dim3(8192), dim3(256), 0, stream, CATh, wo, bo, (float*)d_out);
}

// Round 3
// 2998.938 us; speedup vs baseline: 1.2702x; 1.2702x over previous
//
#include <hip/hip_runtime.h>
#include <hip/hip_fp16.h>

#define TDIM 512
#define FDIM 80

typedef _Float16 f16x8 __attribute__((ext_vector_type(8)));
typedef float f32x4 __attribute__((ext_vector_type(4)));

// ---------------- conv 3x3, 64->64, in NHWC [B,T,F,64] fp32, out [B,C,T,F] fp16 ----------------
__global__ __launch_bounds__(256) void k_conv_in(
    const float* __restrict__ x, const float* __restrict__ w,
    const float* __restrict__ bias, __half* __restrict__ y)
{
  __shared__ float tile[246 * 64];   // rows: ky*82 + (f+1), stride 64 (ci)
  const int bid = blockIdx.x;
  const int b = bid >> 9, t = bid & 511;
  const int tid = threadIdx.x;

  for (int idx = tid; idx < 246 * 16; idx += 256) {
    int row = idx >> 4, cq = idx & 15;
    int ky = row / 82, fi = row - ky * 82;
    int tt = t + ky - 1, ff = fi - 1;
    float4 v = make_float4(0.f, 0.f, 0.f, 0.f);
    if (tt >= 0 && tt < TDIM && ff >= 0 && ff < FDIM)
      v = *reinterpret_cast<const float4*>(x + (((b * TDIM + tt) * FDIM + ff) << 6) + cq * 4);
    *reinterpret_cast<float4*>(tile + (row << 6) + cq * 4) = v;
  }
  __syncthreads();

  const int cg = tid & 15, fg = tid >> 4;
  const int c0 = cg * 4, f0 = fg * 5;
  float acc[4][5];
  #pragma unroll
  for (int i = 0; i < 4; i++) {
    float bv = bias[c0 + i];
    #pragma unroll
    for (int j = 0; j < 5; j++) acc[i][j] = bv;
  }

  for (int ky = 0; ky < 3; ky++) {
    for (int ciq = 0; ciq < 16; ciq++) {
      const float* tp = tile + ((ky * 82 + f0) << 6) + ciq * 4;
      float4 iv[7];
      #pragma unroll
      for (int d = 0; d < 7; d++) iv[d] = *reinterpret_cast<const float4*>(tp + (d << 6));
      #pragma unroll
      for (int kx = 0; kx < 3; kx++) {
        const float* wp = w + (((ky * 3 + kx) * 64 + ciq * 4) << 6) + c0;
        float4 w0 = *reinterpret_cast<const float4*>(wp);
        float4 w1 = *reinterpret_cast<const float4*>(wp + 64);
        float4 w2 = *reinterpret_cast<const float4*>(wp + 128);
        float4 w3 = *reinterpret_cast<const float4*>(wp + 192);
        #pragma unroll
        for (int ff = 0; ff < 5; ff++) {
          float4 v = iv[ff + kx];
          acc[0][ff] += v.x * w0.x + v.y * w1.x + v.z * w2.x + v.w * w3.x;
          acc[1][ff] += v.x * w0.y + v.y * w1.y + v.z * w2.y + v.w * w3.y;
          acc[2][ff] += v.x * w0.z + v.y * w1.z + v.z * w2.z + v.w * w3.z;
          acc[3][ff] += v.x * w0.w + v.y * w1.w + v.z * w2.w + v.w * w3.w;
        }
      }
    }
  }
  __syncthreads();
  float* yt = tile;                  // overlay: [64][81]
  #pragma unroll
  for (int i = 0; i < 4; i++)
    #pragma unroll
    for (int j = 0; j < 5; j++)
      yt[(c0 + i) * 81 + f0 + j] = acc[i][j];
  __syncthreads();
  for (int it = 0; it < 20; it++) {
    int idx = tid + (it << 8);       // 0..5119
    int c = idx / 80, f = idx - c * 80;
    y[((b * 64 + c) * TDIM + t) * FDIM + f] = __float2half(yt[c * 81 + f]);
  }
}

// ---------------- freq attention (MFMA): per (b,c,qtile64), L=T=512, D=F=80 ----------------
__global__ __launch_bounds__(256) void k_attn_freq(
    const __half* __restrict__ XQ, const __half* __restrict__ XK,
    const __half* __restrict__ XV, __half* __restrict__ CAT)
{
  __shared__ __align__(16) __half Qs[64 * 104];   // [q][k] k zero-padded 80->96, stride 104
  __shared__ __align__(16) __half Ks[32 * 104];   // [m][k] same padding
  __shared__ __align__(16) __half Vt[80 * 40];    // [f][m] transposed V, stride 40
  __shared__ __align__(16) __half Pl[4 * 16 * 40];// per-wave P bounce [16 q][40]

  const int bid = blockIdx.x;
  const int bc = bid & 511, tl = bid >> 9;        // same bc -> same XCD (512%8==0)
  const int b = bc >> 6, c = bc & 63;
  const int t0 = tl * 64;
  const int tid = threadIdx.x;
  const int wv = tid >> 6, ln = tid & 63;
  const int lr = ln & 15, lg = ln >> 4;           // fragment row/col, k-group
  const float qscale = 0.1118033988749895f;       // 1/sqrt(80)

  // ---- stage Q tile [64][104], zero pad cols 80..103
  const __half* Qg = XQ + (size_t)bc * 40960 + (size_t)t0 * 80;
  for (int idx = tid; idx < 64 * 13; idx += 256) {
    int row = idx / 13, cw = idx - row * 13, col = cw * 8;
    f16x8 v;
    #pragma unroll
    for (int j = 0; j < 8; j++) v[j] = (_Float16)0.f;
    if (col < 80) v = *reinterpret_cast<const f16x8*>(Qg + row * 80 + col);
    *reinterpret_cast<f16x8*>(&Qs[row * 104 + col]) = v;
  }
  __syncthreads();

  // per-wave Q fragments, held in registers for all 16 KV iters
  f16x8 qf[3];
  #pragma unroll
  for (int kc = 0; kc < 3; kc++)
    qf[kc] = *reinterpret_cast<const f16x8*>(&Qs[(wv * 16 + lr) * 104 + kc * 32 + lg * 8]);

  f32x4 O[5];
  #pragma unroll
  for (int ft = 0; ft < 5; ft++)
    #pragma unroll
    for (int r = 0; r < 4; r++) O[ft][r] = 0.f;
  float m_r[4], l_r[4];
  #pragma unroll
  for (int r = 0; r < 4; r++) { m_r[r] = -1e30f; l_r[r] = 0.f; }

  const __half* Kg = XK + (size_t)bc * 40960;
  const __half* Vg = XV + (size_t)bc * 40960;

  for (int mt = 0; mt < 16; mt++) {
    __syncthreads();                 // prior iter's Ks/Vt reads complete
    // stage K [32][104]
    for (int idx = tid; idx < 32 * 13; idx += 256) {
      int row = idx / 13, cw = idx - row * 13, col = cw * 8;
      f16x8 v;
      #pragma unroll
      for (int j = 0; j < 8; j++) v[j] = (_Float16)0.f;
      if (col < 80) v = *reinterpret_cast<const f16x8*>(Kg + (mt * 32 + row) * 80 + col);
      *reinterpret_cast<f16x8*>(&Ks[row * 104 + col]) = v;
    }
    // stage V transposed: Vt[f][m]
    for (int idx = tid; idx < 40 * 32; idx += 256) {
      int fw = idx >> 5, m = idx & 31;
      int f = fw * 2;
      __half2 hv = *reinterpret_cast<const __half2*>(Vg + (mt * 32 + m) * 80 + f);
      Vt[f * 40 + m] = __low2half(hv);
      Vt[(f + 1) * 40 + m] = __high2half(hv);
    }
    __syncthreads();

    // ---- QK^T: S[16 q][32 m] per wave
    f32x4 S0, S1;
    #pragma unroll
    for (int r = 0; r < 4; r++) { S0[r] = 0.f; S1[r] = 0.f; }
    #pragma unroll
    for (int kc = 0; kc < 3; kc++) {
      f16x8 k0 = *reinterpret_cast<const f16x8*>(&Ks[lr * 104 + kc * 32 + lg * 8]);
      f16x8 k1 = *reinterpret_cast<const f16x8*>(&Ks[(16 + lr) * 104 + kc * 32 + lg * 8]);
      S0 = __builtin_amdgcn_mfma_f32_16x16x32_f16(qf[kc], k0, S0, 0, 0, 0);
      S1 = __builtin_amdgcn_mfma_f32_16x16x32_f16(qf[kc], k1, S1, 0, 0, 0);
    }

    // ---- online softmax (rows = (lg*4+r), cols = lr / 16+lr)
    float p0[4], p1[4], corr[4];
    #pragma unroll
    for (int r = 0; r < 4; r++) {
      float s0 = S0[r] * qscale, s1 = S1[r] * qscale;
      float tm = fmaxf(s0, s1);
      tm = fmaxf(tm, __shfl_xor(tm, 1, 16));
      tm = fmaxf(tm, __shfl_xor(tm, 2, 16));
      tm = fmaxf(tm, __shfl_xor(tm, 4, 16));
      tm = fmaxf(tm, __shfl_xor(tm, 8, 16));
      float mn = fmaxf(m_r[r], tm);
      corr[r] = __expf(m_r[r] - mn);
      m_r[r] = mn;
      p0[r] = __expf(s0 - mn);
      p1[r] = __expf(s1 - mn);
      float ls = p0[r] + p1[r];
      ls += __shfl_xor(ls, 1, 16);
      ls += __shfl_xor(ls, 2, 16);
      ls += __shfl_xor(ls, 4, 16);
      ls += __shfl_xor(ls, 8, 16);
      l_r[r] = l_r[r] * corr[r] + ls;
    }
    #pragma unroll
    for (int ft = 0; ft < 5; ft++)
      #pragma unroll
      for (int r = 0; r < 4; r++) O[ft][r] *= corr[r];

    // ---- P (C-layout) -> wave-private LDS -> A-layout fragment
    __half* pw = &Pl[wv * 640];
    #pragma unroll
    for (int r = 0; r < 4; r++) {
      int row = lg * 4 + r;
      pw[row * 40 + lr]      = __float2half(p0[r]);
      pw[row * 40 + 16 + lr] = __float2half(p1[r]);
    }
    asm volatile("s_waitcnt lgkmcnt(0)" ::: "memory");
    f16x8 pf = *reinterpret_cast<const f16x8*>(&pw[lr * 40 + lg * 8]);

    // ---- PV: O[16 q][80 f] += P(16x32) * V(32x80)
    #pragma unroll
    for (int ft = 0; ft < 5; ft++) {
      f16x8 vf = *reinterpret_cast<const f16x8*>(&Vt[(ft * 16 + lr) * 40 + lg * 8]);
      O[ft] = __builtin_amdgcn_mfma_f32_16x16x32_f16(pf, vf, O[ft], 0, 0, 0);
    }
  }

  // ---- epilogue: normalize, write CAT channels 64..127
  #pragma unroll
  for (int r = 0; r < 4; r++) {
    float inv = 1.f / l_r[r];
    int t = t0 + wv * 16 + lg * 4 + r;
    size_t base = (((size_t)b * TDIM + t) * FDIM) * 128 + 64 + c;
    #pragma unroll
    for (int ft = 0; ft < 5; ft++) {
      int f = ft * 16 + lr;
      CAT[base + (size_t)f * 128] = __float2half(O[ft][r] * inv);
    }
  }
}

// ---------------- time attention: per (b,c), L=F=80, D=T=512 ----------------
__global__ __launch_bounds__(256) void k_attn_time(
    const __half* __restrict__ XQ, const __half* __restrict__ XK,
    const __half* __restrict__ XV, __half* __restrict__ CAT)
{
  __shared__ float Qc[64 * 20];      // [t][fi] 16 f-cols, stride 20
  __shared__ float Kc[64 * 84];      // [t][g] stride 84 (also reused for V)
  __shared__ float Sp[16 * 84];      // [fi][g]
  const int bid = blockIdx.x;
  const int bc = bid & 511, fb = bid >> 9;
  const int b = bc >> 6, c = bc & 63;
  const int f0 = fb * 16;
  const int tid = threadIdx.x;
  const float tscale = 0.04419417382415922f; // 1/sqrt(512)
  const int fy = tid >> 4, gx = tid & 15;
  const __half* Qp = XQ + bc * 40960;
  const __half* Kp = XK + bc * 40960;
  const __half* Vp = XV + bc * 40960;

  float acc[5] = {0.f, 0.f, 0.f, 0.f, 0.f};
  for (int tc = 0; tc < 8; tc++) {
    __syncthreads();
    for (int idx = tid; idx < 64 * 16; idx += 256) {
      int t = idx >> 4, fi = idx & 15;
      Qc[t * 20 + fi] = __half2float(Qp[(tc * 64 + t) * 80 + f0 + fi]);
    }
    for (int idx = tid; idx < 64 * 80; idx += 256) {
      int t = idx / 80, g = idx - t * 80;
      Kc[t * 84 + g] = __half2float(Kp[(tc * 64 + t) * 80 + g]);
    }
    __syncthreads();
    for (int t = 0; t < 64; t++) {
      float qv = Qc[t * 20 + fy];
      #pragma unroll
      for (int i = 0; i < 5; i++) acc[i] += qv * Kc[t * 84 + gx * 5 + i];
    }
  }
  #pragma unroll
  for (int i = 0; i < 5; i++) Sp[fy * 84 + gx * 5 + i] = acc[i] * tscale;
  __syncthreads();

  float mx = -1e30f;
  float pv[5];
  #pragma unroll
  for (int j = 0; j < 5; j++) mx = fmaxf(mx, Sp[fy * 84 + gx + 16 * j]);
  #pragma unroll
  for (int s = 1; s < 16; s <<= 1) mx = fmaxf(mx, __shfl_xor(mx, s, 16));
  float ls = 0.f;
  #pragma unroll
  for (int j = 0; j < 5; j++) { pv[j] = __expf(Sp[fy * 84 + gx + 16 * j] - mx); ls += pv[j]; }
  #pragma unroll
  for (int s = 1; s < 16; s <<= 1) ls += __shfl_xor(ls, s, 16);
  float inv = 1.f / ls;
  __syncthreads();
  #pragma unroll
  for (int j = 0; j < 5; j++) Sp[fy * 84 + gx + 16 * j] = pv[j] * inv;

  for (int tc = 0; tc < 8; tc++) {
    __syncthreads();
    for (int idx = tid; idx < 64 * 80; idx += 256) {
      int t = idx / 80, g = idx - t * 80;
      Kc[t * 84 + g] = __half2float(Vp[(tc * 64 + t) * 80 + g]);
    }
    __syncthreads();
    float o[4] = {0.f, 0.f, 0.f, 0.f};
    for (int g = 0; g < 80; g++) {
      float p = Sp[fy * 84 + g];
      #pragma unroll
      for (int j = 0; j < 4; j++) o[j] += p * Kc[(gx + 16 * j) * 84 + g];
    }
    #pragma unroll
    for (int j = 0; j < 4; j++) {
      int t = tc * 64 + gx + 16 * j;
      CAT[((b * TDIM + t) * FDIM + f0 + fy) * 128 + c] = __float2half(o[j]);
    }
  }
}

// ---------------- conv 3x3, 128->64, in [B,T,F,128] fp16 (CAT), out NHWC [B,T,F,64] fp32 ----------------
__global__ __launch_bounds__(256) void k_conv_out(
    const __half* __restrict__ x, const float* __restrict__ w,
    const float* __restrict__ bias, float* __restrict__ out)
{
  __shared__ float tile[126 * 64];   // rows: ky*42 + fi, 64-ch half, stride 64
  const int bid = blockIdx.x;
  const int b = bid >> 10, rem = bid & 1023;
  const int t = rem >> 1, fb = rem & 1;
  const int fbase = fb * 40;
  const int tid = threadIdx.x;
  const int cg = tid & 31, fg = tid >> 5;
  const int c0 = cg * 2, f0 = fg * 5;

  float acc[2][5];
  #pragma unroll
  for (int i = 0; i < 2; i++) {
    float bv = bias[c0 + i];
    #pragma unroll
    for (int j = 0; j < 5; j++) acc[i][j] = bv;
  }

  for (int hh = 0; hh < 2; hh++) {
    __syncthreads();
    for (int idx = tid; idx < 126 * 16; idx += 256) {
      int row = idx >> 4, cq = idx & 15;
      int ky = row / 42, fi = row - ky * 42;
      int tt = t + ky - 1, ff = fbase + fi - 1;
      float4 v = make_float4(0.f, 0.f, 0.f, 0.f);
      if (tt >= 0 && tt < TDIM && ff >= 0 && ff < FDIM) {
        const __half2* hp = reinterpret_cast<const __half2*>(
            x + (((b * TDIM + tt) * FDIM + ff) << 7) + (hh << 6) + cq * 4);
        float2 a = __half22float2(hp[0]), bb = __half22float2(hp[1]);
        v = make_float4(a.x, a.y, bb.x, bb.y);
      }
      *reinterpret_cast<float4*>(tile + (row << 6) + cq * 4) = v;
    }
    __syncthreads();
    for (int ky = 0; ky < 3; ky++) {
      for (int ciq = 0; ciq < 16; ciq++) {
        const float* tp = tile + ((ky * 42 + f0) << 6) + ciq * 4;
        float4 iv[7];
        #pragma unroll
        for (int d = 0; d < 7; d++) iv[d] = *reinterpret_cast<const float4*>(tp + (d << 6));
        #pragma unroll
        for (int kx = 0; kx < 3; kx++) {
          const float* wp = w + (((ky * 3 + kx) * 128 + (hh << 6) + ciq * 4) << 6) + c0;
          float2 w0 = *reinterpret_cast<const float2*>(wp);
          float2 w1 = *reinterpret_cast<const float2*>(wp + 64);
          float2 w2 = *reinterpret_cast<const float2*>(wp + 128);
          float2 w3 = *reinterpret_cast<const float2*>(wp + 192);
          #pragma unroll
          for (int ff = 0; ff < 5; ff++) {
            float4 v = iv[ff + kx];
            acc[0][ff] += v.x * w0.x + v.y * w1.x + v.z * w2.x + v.w * w3.x;
            acc[1][ff] += v.x * w0.y + v.y * w1.y + v.z * w2.y + v.w * w3.y;
          }
        }
      }
    }
  }
  #pragma unroll
  for (int ff = 0; ff < 5; ff++) {
    int f = fbase + f0 + ff;
    float2 o;
    o.x = acc[0][ff]; o.y = acc[1][ff];
    *reinterpret_cast<float2*>(out + (((b * TDIM + t) * FDIM + f) << 6) + c0) = o;
  }
}

extern "C" void kernel_launch(void* const* d_in, const int* in_sizes, int n_in,
                              void* d_out, int out_size, void* d_ws, size_t ws_size,
                              hipStream_t stream)
{
  const float* q  = (const float*)d_in[0];
  const float* k  = (const float*)d_in[1];
  const float* v  = (const float*)d_in[2];
  const float* wq = (const float*)d_in[3];
  const float* bq = (const float*)d_in[4];
  const float* wk = (const float*)d_in[5];
  const float* bk = (const float*)d_in[6];
  const float* wv = (const float*)d_in[7];
  const float* bv = (const float*)d_in[8];
  const float* wo = (const float*)d_in[9];
  const float* bo = (const float*)d_in[10];

  const size_t PLANE = (size_t)8 * 64 * 512 * 80;   // 20,971,520 elements
  __half* XQh  = (__half*)d_ws;                     // PLANE halves
  __half* XKh  = XQh + PLANE;                       // PLANE halves
  __half* CATh = XKh + PLANE;                       // 2*PLANE halves  [B,T,F,128]
  __half* XVh  = (__half*)d_out;                    // PLANE halves; dead before k_conv_out writes

  hipLaunchKernelGGL(k_conv_in, dim3(4096), dim3(256), 0, stream, q, wq, bq, XQh);
  hipLaunchKernelGGL(k_conv_in, dim3(4096), dim3(256), 0, stream, k, wk, bk, XKh);
  hipLaunchKernelGGL(k_conv_in, dim3(4096), dim3(256), 0, stream, v, wv, bv, XVh);
  hipLaunchKernelGGL(k_attn_freq, dim3(4096), dim3(256), 0, stream, XQh, XKh, XVh, CATh);
  hipLaunchKernelGGL(k_attn_time, dim3(2560), dim3(256), 0, stream, XQh, XKh, XVh, CATh);
  hipLaunchKernelGGL(k_conv_out, dim3(8192), dim3(256), 0, stream, CATh, wo, bo, (float*)d_out);
}

// Round 4
// 1189.517 us; speedup vs baseline: 3.2023x; 2.5211x over previous
//
#include <hip/hip_runtime.h>
#include <hip/hip_fp16.h>

#define TDIM 512
#define FDIM 80

typedef _Float16 f16x8 __attribute__((ext_vector_type(8)));
typedef _Float16 f16x4 __attribute__((ext_vector_type(4)));
typedef float f32x4 __attribute__((ext_vector_type(4)));

// ---------------- conv 3x3 64->64 via MFMA: in NHWC [B,T,F,64] fp32, out [B,C,T,F] fp16 ----------------
// block = (b,t); 4 waves x 16 out-ch; M=80 f (5 subtiles), K = ky,kx,ci
__global__ __launch_bounds__(256) void k_conv_in(
    const float* __restrict__ x, const float* __restrict__ w,
    const float* __restrict__ bias, __half* __restrict__ y)
{
  __shared__ __align__(16) _Float16 xs[246 * 72];  // [ky*82+fi][ci], fi = f+1, stride 72
  const int bid = blockIdx.x;
  const int b = bid >> 9, t = bid & 511;
  const int tid = threadIdx.x;
  const int wv = tid >> 6, ln = tid & 63;
  const int lr = ln & 15, lg = ln >> 4;
  const int c0 = wv * 16;

  // stage input rows t-1..t+1, f=-1..80 zero-padded, fp32 -> fp16
  for (int idx = tid; idx < 246 * 16; idx += 256) {
    int r2 = idx >> 4, cq = idx & 15;
    int ky = r2 / 82, fi = r2 - ky * 82;
    int tt = t + ky - 1, ff = fi - 1;
    f16x4 h;
    #pragma unroll
    for (int j = 0; j < 4; j++) h[j] = (_Float16)0.f;
    if (tt >= 0 && tt < TDIM && ff >= 0 && ff < FDIM) {
      float4 v = *reinterpret_cast<const float4*>(x + (((b * TDIM + tt) * FDIM + ff) << 6) + cq * 4);
      h[0] = (_Float16)v.x; h[1] = (_Float16)v.y; h[2] = (_Float16)v.z; h[3] = (_Float16)v.w;
    }
    *reinterpret_cast<f16x4*>(&xs[r2 * 72 + cq * 4]) = h;
  }
  __syncthreads();

  float bv = bias[c0 + lr];
  f32x4 acc[5];
  #pragma unroll
  for (int mt = 0; mt < 5; mt++)
    #pragma unroll
    for (int r = 0; r < 4; r++) acc[mt][r] = bv;

  for (int ky = 0; ky < 3; ky++) {
    // B-frags: wf[kx][cc] lane(lr,lg) = w[ky][kx][cc*32+lg*8+j][c0+lr], fp32 gather -> f16
    f16x8 wf[3][2];
    #pragma unroll
    for (int kx = 0; kx < 3; kx++)
      #pragma unroll
      for (int cc = 0; cc < 2; cc++) {
        const float* wp = w + ((ky * 3 + kx) * 64 + cc * 32 + lg * 8) * 64 + c0 + lr;
        #pragma unroll
        for (int j = 0; j < 8; j++) wf[kx][cc][j] = (_Float16)wp[j * 64];
      }
    #pragma unroll
    for (int mt = 0; mt < 5; mt++) {
      #pragma unroll
      for (int kx = 0; kx < 3; kx++) {
        const _Float16* ap = &xs[(ky * 82 + mt * 16 + lr + kx) * 72];
        #pragma unroll
        for (int cc = 0; cc < 2; cc++) {
          f16x8 af = *reinterpret_cast<const f16x8*>(ap + cc * 32 + lg * 8);
          acc[mt] = __builtin_amdgcn_mfma_f32_16x16x32_f16(af, wf[kx][cc], acc[mt], 0, 0, 0);
        }
      }
    }
  }

  // epilogue: D[row=f, col=c]; pack 4 consecutive f into one 8B store
  const int c = c0 + lr;
  #pragma unroll
  for (int mt = 0; mt < 5; mt++) {
    int f0 = mt * 16 + lg * 4;
    f16x4 h;
    #pragma unroll
    for (int r = 0; r < 4; r++) h[r] = (_Float16)acc[mt][r];
    *reinterpret_cast<f16x4*>(y + ((size_t)(b * 64 + c) * TDIM + t) * FDIM + f0) = h;
  }
}

// ---------------- freq attention (MFMA): per (b,c,qtile64), L=T=512, D=F=80 ----------------
__global__ __launch_bounds__(256) void k_attn_freq(
    const __half* __restrict__ XQ, const __half* __restrict__ XK,
    const __half* __restrict__ XV, __half* __restrict__ CAT)
{
  __shared__ __align__(16) __half Qs[64 * 104];
  __shared__ __align__(16) __half Ks[32 * 104];
  __shared__ __align__(16) __half Vt[80 * 40];
  __shared__ __align__(16) __half Pl[4 * 16 * 40];

  const int bid = blockIdx.x;
  const int bc = bid & 511, tl = bid >> 9;
  const int b = bc >> 6, c = bc & 63;
  const int t0 = tl * 64;
  const int tid = threadIdx.x;
  const int wv = tid >> 6, ln = tid & 63;
  const int lr = ln & 15, lg = ln >> 4;
  const float qscale = 0.1118033988749895f;  // 1/sqrt(80)

  const __half* Qg = XQ + (size_t)bc * 40960 + (size_t)t0 * 80;
  for (int idx = tid; idx < 64 * 13; idx += 256) {
    int row = idx / 13, cw = idx - row * 13, col = cw * 8;
    f16x8 v;
    #pragma unroll
    for (int j = 0; j < 8; j++) v[j] = (_Float16)0.f;
    if (col < 80) v = *reinterpret_cast<const f16x8*>(Qg + row * 80 + col);
    *reinterpret_cast<f16x8*>(&Qs[row * 104 + col]) = v;
  }
  __syncthreads();

  f16x8 qf[3];
  #pragma unroll
  for (int kc = 0; kc < 3; kc++)
    qf[kc] = *reinterpret_cast<const f16x8*>(&Qs[(wv * 16 + lr) * 104 + kc * 32 + lg * 8]);

  f32x4 O[5];
  #pragma unroll
  for (int ft = 0; ft < 5; ft++)
    #pragma unroll
    for (int r = 0; r < 4; r++) O[ft][r] = 0.f;
  float m_r[4], l_r[4];
  #pragma unroll
  for (int r = 0; r < 4; r++) { m_r[r] = -1e30f; l_r[r] = 0.f; }

  const __half* Kg = XK + (size_t)bc * 40960;
  const __half* Vg = XV + (size_t)bc * 40960;

  for (int mt = 0; mt < 16; mt++) {
    __syncthreads();
    for (int idx = tid; idx < 32 * 13; idx += 256) {
      int row = idx / 13, cw = idx - row * 13, col = cw * 8;
      f16x8 v;
      #pragma unroll
      for (int j = 0; j < 8; j++) v[j] = (_Float16)0.f;
      if (col < 80) v = *reinterpret_cast<const f16x8*>(Kg + (mt * 32 + row) * 80 + col);
      *reinterpret_cast<f16x8*>(&Ks[row * 104 + col]) = v;
    }
    for (int idx = tid; idx < 40 * 32; idx += 256) {
      int fw = idx >> 5, m = idx & 31;
      int f = fw * 2;
      __half2 hv = *reinterpret_cast<const __half2*>(Vg + (mt * 32 + m) * 80 + f);
      Vt[f * 40 + m] = __low2half(hv);
      Vt[(f + 1) * 40 + m] = __high2half(hv);
    }
    __syncthreads();

    f32x4 S0, S1;
    #pragma unroll
    for (int r = 0; r < 4; r++) { S0[r] = 0.f; S1[r] = 0.f; }
    #pragma unroll
    for (int kc = 0; kc < 3; kc++) {
      f16x8 k0 = *reinterpret_cast<const f16x8*>(&Ks[lr * 104 + kc * 32 + lg * 8]);
      f16x8 k1 = *reinterpret_cast<const f16x8*>(&Ks[(16 + lr) * 104 + kc * 32 + lg * 8]);
      S0 = __builtin_amdgcn_mfma_f32_16x16x32_f16(qf[kc], k0, S0, 0, 0, 0);
      S1 = __builtin_amdgcn_mfma_f32_16x16x32_f16(qf[kc], k1, S1, 0, 0, 0);
    }

    float p0[4], p1[4], corr[4];
    #pragma unroll
    for (int r = 0; r < 4; r++) {
      float s0 = S0[r] * qscale, s1 = S1[r] * qscale;
      float tm = fmaxf(s0, s1);
      tm = fmaxf(tm, __shfl_xor(tm, 1, 16));
      tm = fmaxf(tm, __shfl_xor(tm, 2, 16));
      tm = fmaxf(tm, __shfl_xor(tm, 4, 16));
      tm = fmaxf(tm, __shfl_xor(tm, 8, 16));
      float mn = fmaxf(m_r[r], tm);
      corr[r] = __expf(m_r[r] - mn);
      m_r[r] = mn;
      p0[r] = __expf(s0 - mn);
      p1[r] = __expf(s1 - mn);
      float ls = p0[r] + p1[r];
      ls += __shfl_xor(ls, 1, 16);
      ls += __shfl_xor(ls, 2, 16);
      ls += __shfl_xor(ls, 4, 16);
      ls += __shfl_xor(ls, 8, 16);
      l_r[r] = l_r[r] * corr[r] + ls;
    }
    #pragma unroll
    for (int ft = 0; ft < 5; ft++)
      #pragma unroll
      for (int r = 0; r < 4; r++) O[ft][r] *= corr[r];

    __half* pw = &Pl[wv * 640];
    #pragma unroll
    for (int r = 0; r < 4; r++) {
      int row = lg * 4 + r;
      pw[row * 40 + lr]      = __float2half(p0[r]);
      pw[row * 40 + 16 + lr] = __float2half(p1[r]);
    }
    asm volatile("s_waitcnt lgkmcnt(0)" ::: "memory");
    f16x8 pf = *reinterpret_cast<const f16x8*>(&pw[lr * 40 + lg * 8]);

    #pragma unroll
    for (int ft = 0; ft < 5; ft++) {
      f16x8 vf = *reinterpret_cast<const f16x8*>(&Vt[(ft * 16 + lr) * 40 + lg * 8]);
      O[ft] = __builtin_amdgcn_mfma_f32_16x16x32_f16(pf, vf, O[ft], 0, 0, 0);
    }
  }

  #pragma unroll
  for (int r = 0; r < 4; r++) {
    float inv = 1.f / l_r[r];
    int t = t0 + wv * 16 + lg * 4 + r;
    size_t base = (((size_t)b * TDIM + t) * FDIM) * 128 + 64 + c;
    #pragma unroll
    for (int ft = 0; ft < 5; ft++) {
      int f = ft * 16 + lr;
      CAT[base + (size_t)f * 128] = __float2half(O[ft][r] * inv);
    }
  }
}

// ---------------- time attention: per (b,c), L=F=80, D=T=512 ----------------
__global__ __launch_bounds__(256) void k_attn_time(
    const __half* __restrict__ XQ, const __half* __restrict__ XK,
    const __half* __restrict__ XV, __half* __restrict__ CAT)
{
  __shared__ float Qc[64 * 20];
  __shared__ float Kc[64 * 84];
  __shared__ float Sp[16 * 84];
  const int bid = blockIdx.x;
  const int bc = bid & 511, fb = bid >> 9;
  const int b = bc >> 6, c = bc & 63;
  const int f0 = fb * 16;
  const int tid = threadIdx.x;
  const float tscale = 0.04419417382415922f; // 1/sqrt(512)
  const int fy = tid >> 4, gx = tid & 15;
  const __half* Qp = XQ + bc * 40960;
  const __half* Kp = XK + bc * 40960;
  const __half* Vp = XV + bc * 40960;

  float acc[5] = {0.f, 0.f, 0.f, 0.f, 0.f};
  for (int tc = 0; tc < 8; tc++) {
    __syncthreads();
    for (int idx = tid; idx < 64 * 16; idx += 256) {
      int t = idx >> 4, fi = idx & 15;
      Qc[t * 20 + fi] = __half2float(Qp[(tc * 64 + t) * 80 + f0 + fi]);
    }
    for (int idx = tid; idx < 64 * 80; idx += 256) {
      int t = idx / 80, g = idx - t * 80;
      Kc[t * 84 + g] = __half2float(Kp[(tc * 64 + t) * 80 + g]);
    }
    __syncthreads();
    for (int t = 0; t < 64; t++) {
      float qv = Qc[t * 20 + fy];
      #pragma unroll
      for (int i = 0; i < 5; i++) acc[i] += qv * Kc[t * 84 + gx * 5 + i];
    }
  }
  #pragma unroll
  for (int i = 0; i < 5; i++) Sp[fy * 84 + gx * 5 + i] = acc[i] * tscale;
  __syncthreads();

  float mx = -1e30f;
  float pv[5];
  #pragma unroll
  for (int j = 0; j < 5; j++) mx = fmaxf(mx, Sp[fy * 84 + gx + 16 * j]);
  #pragma unroll
  for (int s = 1; s < 16; s <<= 1) mx = fmaxf(mx, __shfl_xor(mx, s, 16));
  float ls = 0.f;
  #pragma unroll
  for (int j = 0; j < 5; j++) { pv[j] = __expf(Sp[fy * 84 + gx + 16 * j] - mx); ls += pv[j]; }
  #pragma unroll
  for (int s = 1; s < 16; s <<= 1) ls += __shfl_xor(ls, s, 16);
  float inv = 1.f / ls;
  __syncthreads();
  #pragma unroll
  for (int j = 0; j < 5; j++) Sp[fy * 84 + gx + 16 * j] = pv[j] * inv;

  for (int tc = 0; tc < 8; tc++) {
    __syncthreads();
    for (int idx = tid; idx < 64 * 80; idx += 256) {
      int t = idx / 80, g = idx - t * 80;
      Kc[t * 84 + g] = __half2float(Vp[(tc * 64 + t) * 80 + g]);
    }
    __syncthreads();
    float o[4] = {0.f, 0.f, 0.f, 0.f};
    for (int g = 0; g < 80; g++) {
      float p = Sp[fy * 84 + g];
      #pragma unroll
      for (int j = 0; j < 4; j++) o[j] += p * Kc[(gx + 16 * j) * 84 + g];
    }
    #pragma unroll
    for (int j = 0; j < 4; j++) {
      int t = tc * 64 + gx + 16 * j;
      CAT[((b * TDIM + t) * FDIM + f0 + fy) * 128 + c] = __float2half(o[j]);
    }
  }
}

// ---------------- conv 3x3 128->64 via MFMA: in [B,T,F,128] fp16 (CAT), out NHWC [B,T,F,64] fp32 ----------------
__global__ __launch_bounds__(256) void k_conv_out(
    const __half* __restrict__ x, const float* __restrict__ w,
    const float* __restrict__ bias, float* __restrict__ out)
{
  __shared__ __align__(16) _Float16 xs[246 * 136];  // [ky*82+fi][ci], stride 136
  const int bid = blockIdx.x;
  const int b = bid >> 9, t = bid & 511;
  const int tid = threadIdx.x;
  const int wv = tid >> 6, ln = tid & 63;
  const int lr = ln & 15, lg = ln >> 4;
  const int c0 = wv * 16;

  // stage CAT rows t-1..t+1, f=-1..80 zero-padded (already fp16)
  for (int idx = tid; idx < 246 * 16; idx += 256) {
    int r2 = idx >> 4, cq = idx & 15;
    int ky = r2 / 82, fi = r2 - ky * 82;
    int tt = t + ky - 1, ff = fi - 1;
    f16x8 h;
    #pragma unroll
    for (int j = 0; j < 8; j++) h[j] = (_Float16)0.f;
    if (tt >= 0 && tt < TDIM && ff >= 0 && ff < FDIM)
      h = *reinterpret_cast<const f16x8*>(x + (((size_t)(b * TDIM + tt) * FDIM + ff) << 7) + cq * 8);
    *reinterpret_cast<f16x8*>(&xs[r2 * 136 + cq * 8]) = h;
  }
  __syncthreads();

  float bv = bias[c0 + lr];
  f32x4 acc[5];
  #pragma unroll
  for (int mt = 0; mt < 5; mt++)
    #pragma unroll
    for (int r = 0; r < 4; r++) acc[mt][r] = bv;

  for (int ky = 0; ky < 3; ky++) {
    // B-frags: wf[kx][cc] lane(lr,lg) = w[ky][kx][cc*32+lg*8+j][c0+lr]
    f16x8 wf[3][4];
    #pragma unroll
    for (int kx = 0; kx < 3; kx++)
      #pragma unroll
      for (int cc = 0; cc < 4; cc++) {
        const float* wp = w + ((ky * 3 + kx) * 128 + cc * 32 + lg * 8) * 64 + c0 + lr;
        #pragma unroll
        for (int j = 0; j < 8; j++) wf[kx][cc][j] = (_Float16)wp[j * 64];
      }
    #pragma unroll
    for (int mt = 0; mt < 5; mt++) {
      #pragma unroll
      for (int kx = 0; kx < 3; kx++) {
        const _Float16* ap = &xs[(ky * 82 + mt * 16 + lr + kx) * 136];
        #pragma unroll
        for (int cc = 0; cc < 4; cc++) {
          f16x8 af = *reinterpret_cast<const f16x8*>(ap + cc * 32 + lg * 8);
          acc[mt] = __builtin_amdgcn_mfma_f32_16x16x32_f16(af, wf[kx][cc], acc[mt], 0, 0, 0);
        }
      }
    }
  }

  // epilogue: D[row=f, col=c] -> out[b,t,f,c] fp32
  const int c = c0 + lr;
  #pragma unroll
  for (int mt = 0; mt < 5; mt++) {
    #pragma unroll
    for (int r = 0; r < 4; r++) {
      int f = mt * 16 + lg * 4 + r;
      out[((size_t)(b * TDIM + t) * FDIM + f) * 64 + c] = acc[mt][r];
    }
  }
}

extern "C" void kernel_launch(void* const* d_in, const int* in_sizes, int n_in,
                              void* d_out, int out_size, void* d_ws, size_t ws_size,
                              hipStream_t stream)
{
  const float* q  = (const float*)d_in[0];
  const float* k  = (const float*)d_in[1];
  const float* v  = (const float*)d_in[2];
  const float* wq = (const float*)d_in[3];
  const float* bq = (const float*)d_in[4];
  const float* wk = (const float*)d_in[5];
  const float* bk = (const float*)d_in[6];
  const float* wv = (const float*)d_in[7];
  const float* bv = (const float*)d_in[8];
  const float* wo = (const float*)d_in[9];
  const float* bo = (const float*)d_in[10];

  const size_t PLANE = (size_t)8 * 64 * 512 * 80;   // 20,971,520 elements
  __half* XQh  = (__half*)d_ws;                     // PLANE halves
  __half* XKh  = XQh + PLANE;                       // PLANE halves
  __half* CATh = XKh + PLANE;                       // 2*PLANE halves  [B,T,F,128]
  __half* XVh  = (__half*)d_out;                    // PLANE halves; dead before k_conv_out writes

  hipLaunchKernelGGL(k_conv_in, dim3(4096), dim3(256), 0, stream, q, wq, bq, XQh);
  hipLaunchKernelGGL(k_conv_in, dim3(4096), dim3(256), 0, stream, k, wk, bk, XKh);
  hipLaunchKernelGGL(k_conv_in, dim3(4096), dim3(256), 0, stream, v, wv, bv, XVh);
  hipLaunchKernelGGL(k_attn_freq, dim3(4096), dim3(256), 0, stream, XQh, XKh, XVh, CATh);
  hipLaunchKernelGGL(k_attn_time, dim3(2560), dim3(256), 0, stream, XQh, XKh, XVh, CATh);
  hipLaunchKernelGGL(k_conv_out, dim3(4096), dim3(256), 0, stream, CATh, wo, bo, (float*)d_out);
}

// Round 6
// 1018.513 us; speedup vs baseline: 3.7399x; 1.1679x over previous
//
#include <hip/hip_runtime.h>
#include <hip/hip_fp16.h>

#define TDIM 512
#define FDIM 80

typedef _Float16 f16x8 __attribute__((ext_vector_type(8)));
typedef _Float16 f16x4 __attribute__((ext_vector_type(4)));
typedef _Float16 f16x2 __attribute__((ext_vector_type(2)));
typedef float f32x4 __attribute__((ext_vector_type(4)));

// ---------------- conv 3x3 64->64 via MFMA: in NHWC [B,T,F,64] fp32, out [B,C,T,F] fp16 ----------------
__global__ __launch_bounds__(256) void k_conv_in(
    const float* __restrict__ x, const float* __restrict__ w,
    const float* __restrict__ bias, __half* __restrict__ y)
{
  __shared__ __align__(16) _Float16 xs[246 * 72];  // [ky*82+fi][ci], fi = f+1, stride 72
  const int bid = blockIdx.x;
  const int b = bid >> 9, t = bid & 511;
  const int tid = threadIdx.x;
  const int wv = tid >> 6, ln = tid & 63;
  const int lr = ln & 15, lg = ln >> 4;
  const int c0 = wv * 16;

  for (int idx = tid; idx < 246 * 16; idx += 256) {
    int r2 = idx >> 4, cq = idx & 15;
    int ky = r2 / 82, fi = r2 - ky * 82;
    int tt = t + ky - 1, ff = fi - 1;
    f16x4 h;
    #pragma unroll
    for (int j = 0; j < 4; j++) h[j] = (_Float16)0.f;
    if (tt >= 0 && tt < TDIM && ff >= 0 && ff < FDIM) {
      float4 v = *reinterpret_cast<const float4*>(x + (((b * TDIM + tt) * FDIM + ff) << 6) + cq * 4);
      h[0] = (_Float16)v.x; h[1] = (_Float16)v.y; h[2] = (_Float16)v.z; h[3] = (_Float16)v.w;
    }
    *reinterpret_cast<f16x4*>(&xs[r2 * 72 + cq * 4]) = h;
  }
  __syncthreads();

  float bv = bias[c0 + lr];
  f32x4 acc[5];
  #pragma unroll
  for (int mt = 0; mt < 5; mt++)
    #pragma unroll
    for (int r = 0; r < 4; r++) acc[mt][r] = bv;

  for (int ky = 0; ky < 3; ky++) {
    f16x8 wf[3][2];
    #pragma unroll
    for (int kx = 0; kx < 3; kx++)
      #pragma unroll
      for (int cc = 0; cc < 2; cc++) {
        const float* wp = w + ((ky * 3 + kx) * 64 + cc * 32 + lg * 8) * 64 + c0 + lr;
        #pragma unroll
        for (int j = 0; j < 8; j++) wf[kx][cc][j] = (_Float16)wp[j * 64];
      }
    #pragma unroll
    for (int mt = 0; mt < 5; mt++) {
      #pragma unroll
      for (int kx = 0; kx < 3; kx++) {
        const _Float16* ap = &xs[(ky * 82 + mt * 16 + lr + kx) * 72];
        #pragma unroll
        for (int cc = 0; cc < 2; cc++) {
          f16x8 af = *reinterpret_cast<const f16x8*>(ap + cc * 32 + lg * 8);
          acc[mt] = __builtin_amdgcn_mfma_f32_16x16x32_f16(af, wf[kx][cc], acc[mt], 0, 0, 0);
        }
      }
    }
  }

  const int c = c0 + lr;
  #pragma unroll
  for (int mt = 0; mt < 5; mt++) {
    int f0 = mt * 16 + lg * 4;
    f16x4 h;
    #pragma unroll
    for (int r = 0; r < 4; r++) h[r] = (_Float16)acc[mt][r];
    *reinterpret_cast<f16x4*>(y + ((size_t)(b * 64 + c) * TDIM + t) * FDIM + f0) = h;
  }
}

// ---------------- freq attention (MFMA, KVBLK=64, reg-prefetch): per (b,c,qtile64) ----------------
__global__ __launch_bounds__(256) void k_attn_freq(
    const __half* __restrict__ XQ, const __half* __restrict__ XK,
    const __half* __restrict__ XV, __half* __restrict__ CAT)
{
  __shared__ __align__(16) _Float16 Ks[64 * 104];   // [m][k], cols 80..103 pad (zeroed once)
  __shared__ __align__(16) _Float16 Vt[80 * 72];    // [f][m] transposed V, stride 72
  __shared__ __align__(16) _Float16 Pl[4 * 16 * 72];// per-wave P bounce [16 q][72]

  const int bid = blockIdx.x;
  const int bc = bid & 511, tl = bid >> 9;          // same bc -> same XCD (512%8==0)
  const int b = bc >> 6, c = bc & 63;
  const int t0 = tl * 64;
  const int tid = threadIdx.x;
  const int wv = tid >> 6, ln = tid & 63;
  const int lr = ln & 15, lg = ln >> 4;
  const float qscale = 0.1118033988749895f;         // 1/sqrt(80)

  const _Float16* Qg = (const _Float16*)XQ + (size_t)bc * 40960 + (size_t)t0 * 80;
  const _Float16* Kg = (const _Float16*)XK + (size_t)bc * 40960;
  const _Float16* Vg = (const _Float16*)XV + (size_t)bc * 40960;

  // Q fragments direct from global (pad k=80..95 with zeros in registers)
  f16x8 qf[3];
  qf[0] = *reinterpret_cast<const f16x8*>(Qg + (wv * 16 + lr) * 80 + lg * 8);
  qf[1] = *reinterpret_cast<const f16x8*>(Qg + (wv * 16 + lr) * 80 + 32 + lg * 8);
  {
    f16x8 z;
    #pragma unroll
    for (int j = 0; j < 8; j++) z[j] = (_Float16)0.f;
    qf[2] = (lg < 2) ? *reinterpret_cast<const f16x8*>(Qg + (wv * 16 + lr) * 80 + 64 + lg * 8) : z;
  }

  // zero K pad cols 80..103 once (stays zero; staging only writes cols 0..79)
  for (int idx = tid; idx < 192; idx += 256) {      // 64 rows x 3 chunks
    int row = idx / 3, cw = idx - row * 3;
    f16x8 z;
    #pragma unroll
    for (int j = 0; j < 8; j++) z[j] = (_Float16)0.f;
    *reinterpret_cast<f16x8*>(&Ks[row * 104 + 80 + cw * 8]) = z;
  }

  // K tile = 64x80 halves = 640 f16x8 chunks: i = tid, tid+256, tid+512(<128)
  // V tile = 64x80 halves = 2560 f16x2 chunks: i = tid + s*256, s=0..9
  f16x8 kreg0, kreg1, kreg2;
  f16x2 vreg[10];
  {
    int i0 = tid, r0 = i0 / 10, w0 = i0 - r0 * 10;
    kreg0 = *reinterpret_cast<const f16x8*>(Kg + r0 * 80 + w0 * 8);
    int i1 = tid + 256, r1 = i1 / 10, w1 = i1 - r1 * 10;
    kreg1 = *reinterpret_cast<const f16x8*>(Kg + r1 * 80 + w1 * 8);
    if (tid < 128) {
      int i2 = tid + 512, r2 = i2 / 10, w2 = i2 - r2 * 10;
      kreg2 = *reinterpret_cast<const f16x8*>(Kg + r2 * 80 + w2 * 8);
    }
    #pragma unroll
    for (int s = 0; s < 10; s++) {
      int ix = tid + s * 256, m = ix / 40, f2 = ix - m * 40;
      vreg[s] = *reinterpret_cast<const f16x2*>(Vg + m * 80 + f2 * 2);
    }
  }

  f32x4 O[5];
  #pragma unroll
  for (int ft = 0; ft < 5; ft++)
    #pragma unroll
    for (int r = 0; r < 4; r++) O[ft][r] = 0.f;
  float m_r[4], l_r[4];
  #pragma unroll
  for (int r = 0; r < 4; r++) { m_r[r] = -1e30f; l_r[r] = 0.f; }

  for (int kt = 0; kt < 8; kt++) {
    __syncthreads();                 // prior compute done reading LDS
    // ---- store staged regs -> LDS
    {
      int i0 = tid, r0 = i0 / 10, w0 = i0 - r0 * 10;
      *reinterpret_cast<f16x8*>(&Ks[r0 * 104 + w0 * 8]) = kreg0;
      int i1 = tid + 256, r1 = i1 / 10, w1 = i1 - r1 * 10;
      *reinterpret_cast<f16x8*>(&Ks[r1 * 104 + w1 * 8]) = kreg1;
      if (tid < 128) {
        int i2 = tid + 512, r2 = i2 / 10, w2 = i2 - r2 * 10;
        *reinterpret_cast<f16x8*>(&Ks[r2 * 104 + w2 * 8]) = kreg2;
      }
      #pragma unroll
      for (int s = 0; s < 10; s++) {
        int ix = tid + s * 256, m = ix / 40, f2 = ix - m * 40;
        Vt[(2 * f2) * 72 + m]     = vreg[s][0];
        Vt[(2 * f2 + 1) * 72 + m] = vreg[s][1];
      }
    }
    // ---- issue prefetch of next tile (hidden under compute)
    if (kt < 7) {
      const _Float16* Kn = Kg + (kt + 1) * 64 * 80;
      const _Float16* Vn = Vg + (kt + 1) * 64 * 80;
      int i0 = tid, r0 = i0 / 10, w0 = i0 - r0 * 10;
      kreg0 = *reinterpret_cast<const f16x8*>(Kn + r0 * 80 + w0 * 8);
      int i1 = tid + 256, r1 = i1 / 10, w1 = i1 - r1 * 10;
      kreg1 = *reinterpret_cast<const f16x8*>(Kn + r1 * 80 + w1 * 8);
      if (tid < 128) {
        int i2 = tid + 512, r2 = i2 / 10, w2 = i2 - r2 * 10;
        kreg2 = *reinterpret_cast<const f16x8*>(Kn + r2 * 80 + w2 * 8);
      }
      #pragma unroll
      for (int s = 0; s < 10; s++) {
        int ix = tid + s * 256, m = ix / 40, f2 = ix - m * 40;
        vreg[s] = *reinterpret_cast<const f16x2*>(Vn + m * 80 + f2 * 2);
      }
    }
    __syncthreads();                 // LDS tile ready

    // ---- QK^T: S[16 q][64 m] per wave (12 MFMAs)
    f32x4 S[4];
    #pragma unroll
    for (int ms = 0; ms < 4; ms++)
      #pragma unroll
      for (int r = 0; r < 4; r++) S[ms][r] = 0.f;
    #pragma unroll
    for (int kc = 0; kc < 3; kc++) {
      #pragma unroll
      for (int ms = 0; ms < 4; ms++) {
        f16x8 kf = *reinterpret_cast<const f16x8*>(&Ks[(ms * 16 + lr) * 104 + kc * 32 + lg * 8]);
        S[ms] = __builtin_amdgcn_mfma_f32_16x16x32_f16(qf[kc], kf, S[ms], 0, 0, 0);
      }
    }

    // ---- online softmax (row q = lg*4+r, cols m = ms*16+lr)
    float p[4][4], corr[4];
    #pragma unroll
    for (int r = 0; r < 4; r++) {
      float s0 = S[0][r] * qscale, s1 = S[1][r] * qscale;
      float s2 = S[2][r] * qscale, s3 = S[3][r] * qscale;
      float tm = fmaxf(fmaxf(s0, s1), fmaxf(s2, s3));
      tm = fmaxf(tm, __shfl_xor(tm, 1, 16));
      tm = fmaxf(tm, __shfl_xor(tm, 2, 16));
      tm = fmaxf(tm, __shfl_xor(tm, 4, 16));
      tm = fmaxf(tm, __shfl_xor(tm, 8, 16));
      float mn = fmaxf(m_r[r], tm);
      corr[r] = __expf(m_r[r] - mn);
      m_r[r] = mn;
      p[0][r] = __expf(s0 - mn); p[1][r] = __expf(s1 - mn);
      p[2][r] = __expf(s2 - mn); p[3][r] = __expf(s3 - mn);
      float ls = (p[0][r] + p[1][r]) + (p[2][r] + p[3][r]);
      ls += __shfl_xor(ls, 1, 16);
      ls += __shfl_xor(ls, 2, 16);
      ls += __shfl_xor(ls, 4, 16);
      ls += __shfl_xor(ls, 8, 16);
      l_r[r] = l_r[r] * corr[r] + ls;
    }
    #pragma unroll
    for (int ft = 0; ft < 5; ft++)
      #pragma unroll
      for (int r = 0; r < 4; r++) O[ft][r] *= corr[r];

    // ---- P (C-layout) -> wave-private LDS -> A-layout fragments
    _Float16* pw = &Pl[wv * 16 * 72];
    #pragma unroll
    for (int r = 0; r < 4; r++) {
      int row = lg * 4 + r;
      #pragma unroll
      for (int ms = 0; ms < 4; ms++)
        pw[row * 72 + ms * 16 + lr] = (_Float16)p[ms][r];
    }
    asm volatile("s_waitcnt lgkmcnt(0)" ::: "memory");
    f16x8 pf0 = *reinterpret_cast<const f16x8*>(&pw[lr * 72 + lg * 8]);
    f16x8 pf1 = *reinterpret_cast<const f16x8*>(&pw[lr * 72 + 32 + lg * 8]);

    // ---- PV: O[16 q][80 f] += P(16x64) * V(64x80)  (10 MFMAs)
    #pragma unroll
    for (int ft = 0; ft < 5; ft++) {
      f16x8 vf0 = *reinterpret_cast<const f16x8*>(&Vt[(ft * 16 + lr) * 72 + lg * 8]);
      f16x8 vf1 = *reinterpret_cast<const f16x8*>(&Vt[(ft * 16 + lr) * 72 + 32 + lg * 8]);
      O[ft] = __builtin_amdgcn_mfma_f32_16x16x32_f16(pf0, vf0, O[ft], 0, 0, 0);
      O[ft] = __builtin_amdgcn_mfma_f32_16x16x32_f16(pf1, vf1, O[ft], 0, 0, 0);
    }
  }

  // ---- epilogue: normalize, write CAT channels 64..127
  #pragma unroll
  for (int r = 0; r < 4; r++) {
    float inv = 1.f / l_r[r];
    int t = t0 + wv * 16 + lg * 4 + r;
    size_t base = (((size_t)b * TDIM + t) * FDIM) * 128 + 64 + c;
    #pragma unroll
    for (int ft = 0; ft < 5; ft++) {
      int f = ft * 16 + lr;
      CAT[base + (size_t)f * 128] = __float2half(O[ft][r] * inv);
    }
  }
}

// ---------------- time attention: per (b,c), L=F=80, D=T=512 ----------------
__global__ __launch_bounds__(256) void k_attn_time(
    const __half* __restrict__ XQ, const __half* __restrict__ XK,
    const __half* __restrict__ XV, __half* __restrict__ CAT)
{
  __shared__ float Qc[64 * 20];
  __shared__ float Kc[64 * 84];
  __shared__ float Sp[16 * 84];
  const int bid = blockIdx.x;
  const int bc = bid & 511, fb = bid >> 9;
  const int b = bc >> 6, c = bc & 63;
  const int f0 = fb * 16;
  const int tid = threadIdx.x;
  const float tscale = 0.04419417382415922f; // 1/sqrt(512)
  const int fy = tid >> 4, gx = tid & 15;
  const __half* Qp = XQ + bc * 40960;
  const __half* Kp = XK + bc * 40960;
  const __half* Vp = XV + bc * 40960;

  float acc[5] = {0.f, 0.f, 0.f, 0.f, 0.f};
  for (int tc = 0; tc < 8; tc++) {
    __syncthreads();
    for (int idx = tid; idx < 64 * 16; idx += 256) {
      int t = idx >> 4, fi = idx & 15;
      Qc[t * 20 + fi] = __half2float(Qp[(tc * 64 + t) * 80 + f0 + fi]);
    }
    for (int idx = tid; idx < 64 * 80; idx += 256) {
      int t = idx / 80, g = idx - t * 80;
      Kc[t * 84 + g] = __half2float(Kp[(tc * 64 + t) * 80 + g]);
    }
    __syncthreads();
    for (int t = 0; t < 64; t++) {
      float qv = Qc[t * 20 + fy];
      #pragma unroll
      for (int i = 0; i < 5; i++) acc[i] += qv * Kc[t * 84 + gx * 5 + i];
    }
  }
  #pragma unroll
  for (int i = 0; i < 5; i++) Sp[fy * 84 + gx * 5 + i] = acc[i] * tscale;
  __syncthreads();

  float mx = -1e30f;
  float pv[5];
  #pragma unroll
  for (int j = 0; j < 5; j++) mx = fmaxf(mx, Sp[fy * 84 + gx + 16 * j]);
  #pragma unroll
  for (int s = 1; s < 16; s <<= 1) mx = fmaxf(mx, __shfl_xor(mx, s, 16));
  float ls = 0.f;
  #pragma unroll
  for (int j = 0; j < 5; j++) { pv[j] = __expf(Sp[fy * 84 + gx + 16 * j] - mx); ls += pv[j]; }
  #pragma unroll
  for (int s = 1; s < 16; s <<= 1) ls += __shfl_xor(ls, s, 16);
  float inv = 1.f / ls;
  __syncthreads();
  #pragma unroll
  for (int j = 0; j < 5; j++) Sp[fy * 84 + gx + 16 * j] = pv[j] * inv;

  for (int tc = 0; tc < 8; tc++) {
    __syncthreads();
    for (int idx = tid; idx < 64 * 80; idx += 256) {
      int t = idx / 80, g = idx - t * 80;
      Kc[t * 84 + g] = __half2float(Vp[(tc * 64 + t) * 80 + g]);
    }
    __syncthreads();
    float o[4] = {0.f, 0.f, 0.f, 0.f};
    for (int g = 0; g < 80; g++) {
      float p = Sp[fy * 84 + g];
      #pragma unroll
      for (int j = 0; j < 4; j++) o[j] += p * Kc[(gx + 16 * j) * 84 + g];
    }
    #pragma unroll
    for (int j = 0; j < 4; j++) {
      int t = tc * 64 + gx + 16 * j;
      CAT[((b * TDIM + t) * FDIM + f0 + fy) * 128 + c] = __float2half(o[j]);
    }
  }
}

// ---------------- conv 3x3 128->64 via MFMA: in [B,T,F,128] fp16 (CAT), out NHWC [B,T,F,64] fp32 ----------------
__global__ __launch_bounds__(256) void k_conv_out(
    const __half* __restrict__ x, const float* __restrict__ w,
    const float* __restrict__ bias, float* __restrict__ out)
{
  __shared__ __align__(16) _Float16 xs[246 * 136];
  const int bid = blockIdx.x;
  const int b = bid >> 9, t = bid & 511;
  const int tid = threadIdx.x;
  const int wv = tid >> 6, ln = tid & 63;
  const int lr = ln & 15, lg = ln >> 4;
  const int c0 = wv * 16;

  for (int idx = tid; idx < 246 * 16; idx += 256) {
    int r2 = idx >> 4, cq = idx & 15;
    int ky = r2 / 82, fi = r2 - ky * 82;
    int tt = t + ky - 1, ff = fi - 1;
    f16x8 h;
    #pragma unroll
    for (int j = 0; j < 8; j++) h[j] = (_Float16)0.f;
    if (tt >= 0 && tt < TDIM && ff >= 0 && ff < FDIM)
      h = *reinterpret_cast<const f16x8*>(x + (((size_t)(b * TDIM + tt) * FDIM + ff) << 7) + cq * 8);
    *reinterpret_cast<f16x8*>(&xs[r2 * 136 + cq * 8]) = h;
  }
  __syncthreads();

  float bv = bias[c0 + lr];
  f32x4 acc[5];
  #pragma unroll
  for (int mt = 0; mt < 5; mt++)
    #pragma unroll
    for (int r = 0; r < 4; r++) acc[mt][r] = bv;

  for (int ky = 0; ky < 3; ky++) {
    f16x8 wf[3][4];
    #pragma unroll
    for (int kx = 0; kx < 3; kx++)
      #pragma unroll
      for (int cc = 0; cc < 4; cc++) {
        const float* wp = w + ((ky * 3 + kx) * 128 + cc * 32 + lg * 8) * 64 + c0 + lr;
        #pragma unroll
        for (int j = 0; j < 8; j++) wf[kx][cc][j] = (_Float16)wp[j * 64];
      }
    #pragma unroll
    for (int mt = 0; mt < 5; mt++) {
      #pragma unroll
      for (int kx = 0; kx < 3; kx++) {
        const _Float16* ap = &xs[(ky * 82 + mt * 16 + lr + kx) * 136];
        #pragma unroll
        for (int cc = 0; cc < 4; cc++) {
          f16x8 af = *reinterpret_cast<const f16x8*>(ap + cc * 32 + lg * 8);
          acc[mt] = __builtin_amdgcn_mfma_f32_16x16x32_f16(af, wf[kx][cc], acc[mt], 0, 0, 0);
        }
      }
    }
  }

  const int c = c0 + lr;
  #pragma unroll
  for (int mt = 0; mt < 5; mt++) {
    #pragma unroll
    for (int r = 0; r < 4; r++) {
      int f = mt * 16 + lg * 4 + r;
      out[((size_t)(b * TDIM + t) * FDIM + f) * 64 + c] = acc[mt][r];
    }
  }
}

extern "C" void kernel_launch(void* const* d_in, const int* in_sizes, int n_in,
                              void* d_out, int out_size, void* d_ws, size_t ws_size,
                              hipStream_t stream)
{
  const float* q  = (const float*)d_in[0];
  const float* k  = (const float*)d_in[1];
  const float* v  = (const float*)d_in[2];
  const float* wq = (const float*)d_in[3];
  const float* bq = (const float*)d_in[4];
  const float* wk = (const float*)d_in[5];
  const float* bk = (const float*)d_in[6];
  const float* wv = (const float*)d_in[7];
  const float* bv = (const float*)d_in[8];
  const float* wo = (const float*)d_in[9];
  const float* bo = (const float*)d_in[10];

  const size_t PLANE = (size_t)8 * 64 * 512 * 80;   // 20,971,520 elements
  __half* XQh  = (__half*)d_ws;
  __half* XKh  = XQh + PLANE;
  __half* CATh = XKh + PLANE;                       // [B,T,F,128] fp16
  __half* XVh  = (__half*)d_out;                    // dead before k_conv_out writes

  hipLaunchKernelGGL(k_conv_in, dim3(4096), dim3(256), 0, stream, q, wq, bq, XQh);
  hipLaunchKernelGGL(k_conv_in, dim3(4096), dim3(256), 0, stream, k, wk, bk, XKh);
  hipLaunchKernelGGL(k_conv_in, dim3(4096), dim3(256), 0, stream, v, wv, bv, XVh);
  hipLaunchKernelGGL(k_attn_freq, dim3(4096), dim3(256), 0, stream, XQh, XKh, XVh, CATh);
  hipLaunchKernelGGL(k_attn_time, dim3(2560), dim3(256), 0, stream, XQh, XKh, XVh, CATh);
  hipLaunchKernelGGL(k_conv_out, dim3(4096), dim3(256), 0, stream, CATh, wo, bo, (float*)d_out);
}

// Round 7
// 819.614 us; speedup vs baseline: 4.6475x; 1.2427x over previous
//
#include <hip/hip_runtime.h>
#include <hip/hip_fp16.h>

#define TDIM 512
#define FDIM 80

typedef _Float16 f16x8 __attribute__((ext_vector_type(8)));
typedef _Float16 f16x4 __attribute__((ext_vector_type(4)));
typedef _Float16 f16x2 __attribute__((ext_vector_type(2)));
typedef float f32x4 __attribute__((ext_vector_type(4)));

// ---------------- conv 3x3 64->64 via MFMA: in NHWC [B,T,F,64] fp32, out [B,C,T,F] fp16 ----------------
__global__ __launch_bounds__(256) void k_conv_in(
    const float* __restrict__ x, const float* __restrict__ w,
    const float* __restrict__ bias, __half* __restrict__ y)
{
  __shared__ __align__(16) _Float16 xs[246 * 72];  // [ky*82+fi][ci], fi = f+1, stride 72
  const int bid = blockIdx.x;
  const int b = bid >> 9, t = bid & 511;
  const int tid = threadIdx.x;
  const int wv = tid >> 6, ln = tid & 63;
  const int lr = ln & 15, lg = ln >> 4;
  const int c0 = wv * 16;

  for (int idx = tid; idx < 246 * 16; idx += 256) {
    int r2 = idx >> 4, cq = idx & 15;
    int ky = r2 / 82, fi = r2 - ky * 82;
    int tt = t + ky - 1, ff = fi - 1;
    f16x4 h;
    #pragma unroll
    for (int j = 0; j < 4; j++) h[j] = (_Float16)0.f;
    if (tt >= 0 && tt < TDIM && ff >= 0 && ff < FDIM) {
      float4 v = *reinterpret_cast<const float4*>(x + (((b * TDIM + tt) * FDIM + ff) << 6) + cq * 4);
      h[0] = (_Float16)v.x; h[1] = (_Float16)v.y; h[2] = (_Float16)v.z; h[3] = (_Float16)v.w;
    }
    *reinterpret_cast<f16x4*>(&xs[r2 * 72 + cq * 4]) = h;
  }
  __syncthreads();

  float bv = bias[c0 + lr];
  f32x4 acc[5];
  #pragma unroll
  for (int mt = 0; mt < 5; mt++)
    #pragma unroll
    for (int r = 0; r < 4; r++) acc[mt][r] = bv;

  for (int ky = 0; ky < 3; ky++) {
    f16x8 wf[3][2];
    #pragma unroll
    for (int kx = 0; kx < 3; kx++)
      #pragma unroll
      for (int cc = 0; cc < 2; cc++) {
        const float* wp = w + ((ky * 3 + kx) * 64 + cc * 32 + lg * 8) * 64 + c0 + lr;
        #pragma unroll
        for (int j = 0; j < 8; j++) wf[kx][cc][j] = (_Float16)wp[j * 64];
      }
    #pragma unroll
    for (int mt = 0; mt < 5; mt++) {
      #pragma unroll
      for (int kx = 0; kx < 3; kx++) {
        const _Float16* ap = &xs[(ky * 82 + mt * 16 + lr + kx) * 72];
        #pragma unroll
        for (int cc = 0; cc < 2; cc++) {
          f16x8 af = *reinterpret_cast<const f16x8*>(ap + cc * 32 + lg * 8);
          acc[mt] = __builtin_amdgcn_mfma_f32_16x16x32_f16(af, wf[kx][cc], acc[mt], 0, 0, 0);
        }
      }
    }
  }

  const int c = c0 + lr;
  #pragma unroll
  for (int mt = 0; mt < 5; mt++) {
    int f0 = mt * 16 + lg * 4;
    f16x4 h;
    #pragma unroll
    for (int r = 0; r < 4; r++) h[r] = (_Float16)acc[mt][r];
    *reinterpret_cast<f16x4*>(y + ((size_t)(b * 64 + c) * TDIM + t) * FDIM + f0) = h;
  }
}

// ---------------- freq attention (MFMA, KVBLK=64, reg-prefetch): per (b,c,qtile64) ----------------
__global__ __launch_bounds__(256) void k_attn_freq(
    const __half* __restrict__ XQ, const __half* __restrict__ XK,
    const __half* __restrict__ XV, __half* __restrict__ CAT)
{
  __shared__ __align__(16) _Float16 Ks[64 * 104];   // [m][k], cols 80..103 pad (zeroed once)
  __shared__ __align__(16) _Float16 Vt[80 * 72];    // [f][m] transposed V, stride 72
  __shared__ __align__(16) _Float16 Pl[4 * 16 * 72];// per-wave P bounce [16 q][72]

  const int bid = blockIdx.x;
  const int bc = bid & 511, tl = bid >> 9;          // same bc -> same XCD (512%8==0)
  const int b = bc >> 6, c = bc & 63;
  const int t0 = tl * 64;
  const int tid = threadIdx.x;
  const int wv = tid >> 6, ln = tid & 63;
  const int lr = ln & 15, lg = ln >> 4;
  const float qscale = 0.1118033988749895f;         // 1/sqrt(80)

  const _Float16* Qg = (const _Float16*)XQ + (size_t)bc * 40960 + (size_t)t0 * 80;
  const _Float16* Kg = (const _Float16*)XK + (size_t)bc * 40960;
  const _Float16* Vg = (const _Float16*)XV + (size_t)bc * 40960;

  f16x8 qf[3];
  qf[0] = *reinterpret_cast<const f16x8*>(Qg + (wv * 16 + lr) * 80 + lg * 8);
  qf[1] = *reinterpret_cast<const f16x8*>(Qg + (wv * 16 + lr) * 80 + 32 + lg * 8);
  {
    f16x8 z;
    #pragma unroll
    for (int j = 0; j < 8; j++) z[j] = (_Float16)0.f;
    qf[2] = (lg < 2) ? *reinterpret_cast<const f16x8*>(Qg + (wv * 16 + lr) * 80 + 64 + lg * 8) : z;
  }

  for (int idx = tid; idx < 192; idx += 256) {      // zero K pad cols 80..103
    int row = idx / 3, cw = idx - row * 3;
    f16x8 z;
    #pragma unroll
    for (int j = 0; j < 8; j++) z[j] = (_Float16)0.f;
    *reinterpret_cast<f16x8*>(&Ks[row * 104 + 80 + cw * 8]) = z;
  }

  f16x8 kreg0, kreg1, kreg2;
  f16x2 vreg[10];
  {
    int i0 = tid, r0 = i0 / 10, w0 = i0 - r0 * 10;
    kreg0 = *reinterpret_cast<const f16x8*>(Kg + r0 * 80 + w0 * 8);
    int i1 = tid + 256, r1 = i1 / 10, w1 = i1 - r1 * 10;
    kreg1 = *reinterpret_cast<const f16x8*>(Kg + r1 * 80 + w1 * 8);
    if (tid < 128) {
      int i2 = tid + 512, r2 = i2 / 10, w2 = i2 - r2 * 10;
      kreg2 = *reinterpret_cast<const f16x8*>(Kg + r2 * 80 + w2 * 8);
    }
    #pragma unroll
    for (int s = 0; s < 10; s++) {
      int ix = tid + s * 256, m = ix / 40, f2 = ix - m * 40;
      vreg[s] = *reinterpret_cast<const f16x2*>(Vg + m * 80 + f2 * 2);
    }
  }

  f32x4 O[5];
  #pragma unroll
  for (int ft = 0; ft < 5; ft++)
    #pragma unroll
    for (int r = 0; r < 4; r++) O[ft][r] = 0.f;
  float m_r[4], l_r[4];
  #pragma unroll
  for (int r = 0; r < 4; r++) { m_r[r] = -1e30f; l_r[r] = 0.f; }

  for (int kt = 0; kt < 8; kt++) {
    __syncthreads();
    {
      int i0 = tid, r0 = i0 / 10, w0 = i0 - r0 * 10;
      *reinterpret_cast<f16x8*>(&Ks[r0 * 104 + w0 * 8]) = kreg0;
      int i1 = tid + 256, r1 = i1 / 10, w1 = i1 - r1 * 10;
      *reinterpret_cast<f16x8*>(&Ks[r1 * 104 + w1 * 8]) = kreg1;
      if (tid < 128) {
        int i2 = tid + 512, r2 = i2 / 10, w2 = i2 - r2 * 10;
        *reinterpret_cast<f16x8*>(&Ks[r2 * 104 + w2 * 8]) = kreg2;
      }
      #pragma unroll
      for (int s = 0; s < 10; s++) {
        int ix = tid + s * 256, m = ix / 40, f2 = ix - m * 40;
        Vt[(2 * f2) * 72 + m]     = vreg[s][0];
        Vt[(2 * f2 + 1) * 72 + m] = vreg[s][1];
      }
    }
    if (kt < 7) {
      const _Float16* Kn = Kg + (kt + 1) * 64 * 80;
      const _Float16* Vn = Vg + (kt + 1) * 64 * 80;
      int i0 = tid, r0 = i0 / 10, w0 = i0 - r0 * 10;
      kreg0 = *reinterpret_cast<const f16x8*>(Kn + r0 * 80 + w0 * 8);
      int i1 = tid + 256, r1 = i1 / 10, w1 = i1 - r1 * 10;
      kreg1 = *reinterpret_cast<const f16x8*>(Kn + r1 * 80 + w1 * 8);
      if (tid < 128) {
        int i2 = tid + 512, r2 = i2 / 10, w2 = i2 - r2 * 10;
        kreg2 = *reinterpret_cast<const f16x8*>(Kn + r2 * 80 + w2 * 8);
      }
      #pragma unroll
      for (int s = 0; s < 10; s++) {
        int ix = tid + s * 256, m = ix / 40, f2 = ix - m * 40;
        vreg[s] = *reinterpret_cast<const f16x2*>(Vn + m * 80 + f2 * 2);
      }
    }
    __syncthreads();

    f32x4 S[4];
    #pragma unroll
    for (int ms = 0; ms < 4; ms++)
      #pragma unroll
      for (int r = 0; r < 4; r++) S[ms][r] = 0.f;
    #pragma unroll
    for (int kc = 0; kc < 3; kc++) {
      #pragma unroll
      for (int ms = 0; ms < 4; ms++) {
        f16x8 kf = *reinterpret_cast<const f16x8*>(&Ks[(ms * 16 + lr) * 104 + kc * 32 + lg * 8]);
        S[ms] = __builtin_amdgcn_mfma_f32_16x16x32_f16(qf[kc], kf, S[ms], 0, 0, 0);
      }
    }

    float p[4][4], corr[4];
    #pragma unroll
    for (int r = 0; r < 4; r++) {
      float s0 = S[0][r] * qscale, s1 = S[1][r] * qscale;
      float s2 = S[2][r] * qscale, s3 = S[3][r] * qscale;
      float tm = fmaxf(fmaxf(s0, s1), fmaxf(s2, s3));
      tm = fmaxf(tm, __shfl_xor(tm, 1, 16));
      tm = fmaxf(tm, __shfl_xor(tm, 2, 16));
      tm = fmaxf(tm, __shfl_xor(tm, 4, 16));
      tm = fmaxf(tm, __shfl_xor(tm, 8, 16));
      float mn = fmaxf(m_r[r], tm);
      corr[r] = __expf(m_r[r] - mn);
      m_r[r] = mn;
      p[0][r] = __expf(s0 - mn); p[1][r] = __expf(s1 - mn);
      p[2][r] = __expf(s2 - mn); p[3][r] = __expf(s3 - mn);
      float ls = (p[0][r] + p[1][r]) + (p[2][r] + p[3][r]);
      ls += __shfl_xor(ls, 1, 16);
      ls += __shfl_xor(ls, 2, 16);
      ls += __shfl_xor(ls, 4, 16);
      ls += __shfl_xor(ls, 8, 16);
      l_r[r] = l_r[r] * corr[r] + ls;
    }
    #pragma unroll
    for (int ft = 0; ft < 5; ft++)
      #pragma unroll
      for (int r = 0; r < 4; r++) O[ft][r] *= corr[r];

    _Float16* pw = &Pl[wv * 16 * 72];
    #pragma unroll
    for (int r = 0; r < 4; r++) {
      int row = lg * 4 + r;
      #pragma unroll
      for (int ms = 0; ms < 4; ms++)
        pw[row * 72 + ms * 16 + lr] = (_Float16)p[ms][r];
    }
    asm volatile("s_waitcnt lgkmcnt(0)" ::: "memory");
    f16x8 pf0 = *reinterpret_cast<const f16x8*>(&pw[lr * 72 + lg * 8]);
    f16x8 pf1 = *reinterpret_cast<const f16x8*>(&pw[lr * 72 + 32 + lg * 8]);

    #pragma unroll
    for (int ft = 0; ft < 5; ft++) {
      f16x8 vf0 = *reinterpret_cast<const f16x8*>(&Vt[(ft * 16 + lr) * 72 + lg * 8]);
      f16x8 vf1 = *reinterpret_cast<const f16x8*>(&Vt[(ft * 16 + lr) * 72 + 32 + lg * 8]);
      O[ft] = __builtin_amdgcn_mfma_f32_16x16x32_f16(pf0, vf0, O[ft], 0, 0, 0);
      O[ft] = __builtin_amdgcn_mfma_f32_16x16x32_f16(pf1, vf1, O[ft], 0, 0, 0);
    }
  }

  #pragma unroll
  for (int r = 0; r < 4; r++) {
    float inv = 1.f / l_r[r];
    int t = t0 + wv * 16 + lg * 4 + r;
    size_t base = (((size_t)b * TDIM + t) * FDIM) * 128 + 64 + c;
    #pragma unroll
    for (int ft = 0; ft < 5; ft++) {
      int f = ft * 16 + lr;
      CAT[base + (size_t)f * 128] = __float2half(O[ft][r] * inv);
    }
  }
}

// ---------------- time attention via MFMA: per (b,c); S=Q^T K (K-dim t=512), then PV ----------------
__global__ __launch_bounds__(256) void k_attn_time(
    const __half* __restrict__ XQ, const __half* __restrict__ XK,
    const __half* __restrict__ XV, __half* __restrict__ CAT)
{
  __shared__ __align__(16) char smem[70400];
  _Float16* Qt  = (_Float16*)smem;              // [80][136] phase1
  _Float16* Kt  = Qt + 80 * 136;                // [80][136]
  float*    Sld = (float*)(smem + 43520);       // [80][84] fp32 scores
  _Float16* Pld = (_Float16*)smem;              // [80][104] phase2 (aliases Qt, post-barrier)

  const int bid = blockIdx.x;                   // 512 blocks = (b,c)
  const int b = bid >> 6, c = bid & 63;
  const int tid = threadIdx.x;
  const int wv = tid >> 6, ln = tid & 63;
  const int lr = ln & 15, lg = ln >> 4;
  const float tscale = 0.04419417382415922f;    // 1/sqrt(512)

  const _Float16* Qg = (const _Float16*)XQ + (size_t)bid * 40960;
  const _Float16* Kg = (const _Float16*)XK + (size_t)bid * 40960;
  const _Float16* Vg = (const _Float16*)XV + (size_t)bid * 40960;

  // phase 1: S = Q^T K. 25 16x16 tiles; wave handles ti = wv*7+i (dummy ti>24 -> recompute tile 24)
  f32x4 sacc[7];
  #pragma unroll
  for (int i = 0; i < 7; i++)
    #pragma unroll
    for (int r = 0; r < 4; r++) sacc[i][r] = 0.f;

  for (int tc = 0; tc < 4; tc++) {
    __syncthreads();                            // prior chunk's LDS reads done
    // stage transposed Qt/Kt [f][t_local], t_local in [0,128): f16x2 pair writes
    for (int idx = tid; idx < 640; idx += 256) {
      int t2 = idx / 10, f8 = idx - t2 * 10;
      int tg = tc * 128 + t2 * 2;
      f16x8 qa = *reinterpret_cast<const f16x8*>(Qg + (size_t)tg * 80 + f8 * 8);
      f16x8 qb = *reinterpret_cast<const f16x8*>(Qg + (size_t)(tg + 1) * 80 + f8 * 8);
      f16x8 ka = *reinterpret_cast<const f16x8*>(Kg + (size_t)tg * 80 + f8 * 8);
      f16x8 kb = *reinterpret_cast<const f16x8*>(Kg + (size_t)(tg + 1) * 80 + f8 * 8);
      #pragma unroll
      for (int j = 0; j < 8; j++) {
        int f = f8 * 8 + j;
        f16x2 qp; qp[0] = qa[j]; qp[1] = qb[j];
        f16x2 kp; kp[0] = ka[j]; kp[1] = kb[j];
        *reinterpret_cast<f16x2*>(&Qt[f * 136 + t2 * 2]) = qp;
        *reinterpret_cast<f16x2*>(&Kt[f * 136 + t2 * 2]) = kp;
      }
    }
    __syncthreads();
    #pragma unroll
    for (int i = 0; i < 7; i++) {
      int ti = wv * 7 + i;
      int te = ti < 25 ? ti : 24;
      int mi = te / 5, ni = te - mi * 5;
      #pragma unroll
      for (int kc = 0; kc < 4; kc++) {
        f16x8 aq = *reinterpret_cast<const f16x8*>(&Qt[(mi * 16 + lr) * 136 + kc * 32 + lg * 8]);
        f16x8 bk = *reinterpret_cast<const f16x8*>(&Kt[(ni * 16 + lr) * 136 + kc * 32 + lg * 8]);
        sacc[i] = __builtin_amdgcn_mfma_f32_16x16x32_f16(aq, bk, sacc[i], 0, 0, 0);
      }
    }
  }
  // write S tiles (scaled); Sld region disjoint from Qt/Kt so no barrier needed first
  #pragma unroll
  for (int i = 0; i < 7; i++) {
    int ti = wv * 7 + i;
    if (ti < 25) {
      int mi = ti / 5, ni = ti - mi * 5;
      #pragma unroll
      for (int r = 0; r < 4; r++)
        Sld[(mi * 16 + lg * 4 + r) * 84 + ni * 16 + lr] = sacc[i][r] * tscale;
    }
  }
  __syncthreads();                              // S visible; Qt/Kt dead -> Pld writable

  // softmax over rows of S; write normalized P fp16 (+ zero pad cols 80..103)
  {
    const int fy = tid >> 4, gx = tid & 15;
    #pragma unroll
    for (int pass = 0; pass < 5; pass++) {
      int row = pass * 16 + fy;
      float s[5];
      #pragma unroll
      for (int j = 0; j < 5; j++) s[j] = Sld[row * 84 + gx + 16 * j];
      float mx = fmaxf(fmaxf(fmaxf(s[0], s[1]), fmaxf(s[2], s[3])), s[4]);
      #pragma unroll
      for (int sh = 1; sh < 16; sh <<= 1) mx = fmaxf(mx, __shfl_xor(mx, sh, 16));
      float e[5]; float ls = 0.f;
      #pragma unroll
      for (int j = 0; j < 5; j++) { e[j] = __expf(s[j] - mx); ls += e[j]; }
      #pragma unroll
      for (int sh = 1; sh < 16; sh <<= 1) ls += __shfl_xor(ls, sh, 16);
      float inv = 1.f / ls;
      #pragma unroll
      for (int j = 0; j < 5; j++)
        Pld[row * 104 + gx + 16 * j] = (_Float16)(e[j] * inv);
    }
    for (int idx = tid; idx < 240; idx += 256) {
      int row = idx / 3, cw = idx - row * 3;
      f16x8 z;
      #pragma unroll
      for (int j = 0; j < 8; j++) z[j] = (_Float16)0.f;
      *reinterpret_cast<f16x8*>(&Pld[row * 104 + 80 + cw * 8]) = z;
    }
  }
  __syncthreads();

  // phase 2: out[f][t] = P(80x80) * V^T; A = P rows (regs), B = V rows direct from global
  f16x8 pa[5][3];
  #pragma unroll
  for (int mi = 0; mi < 5; mi++)
    #pragma unroll
    for (int kc = 0; kc < 3; kc++)
      pa[mi][kc] = *reinterpret_cast<const f16x8*>(&Pld[(mi * 16 + lr) * 104 + kc * 32 + lg * 8]);

  #pragma unroll
  for (int j = 0; j < 8; j++) {
    int nt = wv * 8 + j;
    f16x8 vf[3];
    #pragma unroll
    for (int kc = 0; kc < 3; kc++) {
      if (kc < 2) {
        vf[kc] = *reinterpret_cast<const f16x8*>(Vg + (size_t)(nt * 16 + lr) * 80 + kc * 32 + lg * 8);
      } else {
        f16x8 z;
        #pragma unroll
        for (int q = 0; q < 8; q++) z[q] = (_Float16)0.f;
        vf[kc] = (lg < 2) ? *reinterpret_cast<const f16x8*>(Vg + (size_t)(nt * 16 + lr) * 80 + 64 + lg * 8) : z;
      }
    }
    f32x4 oacc[5];
    #pragma unroll
    for (int mi = 0; mi < 5; mi++)
      #pragma unroll
      for (int r = 0; r < 4; r++) oacc[mi][r] = 0.f;
    #pragma unroll
    for (int mi = 0; mi < 5; mi++)
      #pragma unroll
      for (int kc = 0; kc < 3; kc++)
        oacc[mi] = __builtin_amdgcn_mfma_f32_16x16x32_f16(pa[mi][kc], vf[kc], oacc[mi], 0, 0, 0);

    int t = nt * 16 + lr;
    size_t base = (((size_t)b * TDIM + t) * FDIM) * 128 + c;
    #pragma unroll
    for (int mi = 0; mi < 5; mi++)
      #pragma unroll
      for (int r = 0; r < 4; r++) {
        int f = mi * 16 + lg * 4 + r;
        CAT[base + (size_t)f * 128] = __float2half(oacc[mi][r]);
      }
  }
}

// ---------------- conv 3x3 128->64 via MFMA: in [B,T,F,128] fp16 (CAT), out NHWC [B,T,F,64] fp32 ----------------
__global__ __launch_bounds__(256) void k_conv_out(
    const __half* __restrict__ x, const float* __restrict__ w,
    const float* __restrict__ bias, float* __restrict__ out)
{
  __shared__ __align__(16) _Float16 xs[246 * 136];
  const int bid = blockIdx.x;
  const int b = bid >> 9, t = bid & 511;
  const int tid = threadIdx.x;
  const int wv = tid >> 6, ln = tid & 63;
  const int lr = ln & 15, lg = ln >> 4;
  const int c0 = wv * 16;

  for (int idx = tid; idx < 246 * 16; idx += 256) {
    int r2 = idx >> 4, cq = idx & 15;
    int ky = r2 / 82, fi = r2 - ky * 82;
    int tt = t + ky - 1, ff = fi - 1;
    f16x8 h;
    #pragma unroll
    for (int j = 0; j < 8; j++) h[j] = (_Float16)0.f;
    if (tt >= 0 && tt < TDIM && ff >= 0 && ff < FDIM)
      h = *reinterpret_cast<const f16x8*>(x + (((size_t)(b * TDIM + tt) * FDIM + ff) << 7) + cq * 8);
    *reinterpret_cast<f16x8*>(&xs[r2 * 136 + cq * 8]) = h;
  }
  __syncthreads();

  float bv = bias[c0 + lr];
  f32x4 acc[5];
  #pragma unroll
  for (int mt = 0; mt < 5; mt++)
    #pragma unroll
    for (int r = 0; r < 4; r++) acc[mt][r] = bv;

  for (int ky = 0; ky < 3; ky++) {
    f16x8 wf[3][4];
    #pragma unroll
    for (int kx = 0; kx < 3; kx++)
      #pragma unroll
      for (int cc = 0; cc < 4; cc++) {
        const float* wp = w + ((ky * 3 + kx) * 128 + cc * 32 + lg * 8) * 64 + c0 + lr;
        #pragma unroll
        for (int j = 0; j < 8; j++) wf[kx][cc][j] = (_Float16)wp[j * 64];
      }
    #pragma unroll
    for (int mt = 0; mt < 5; mt++) {
      #pragma unroll
      for (int kx = 0; kx < 3; kx++) {
        const _Float16* ap = &xs[(ky * 82 + mt * 16 + lr + kx) * 136];
        #pragma unroll
        for (int cc = 0; cc < 4; cc++) {
          f16x8 af = *reinterpret_cast<const f16x8*>(ap + cc * 32 + lg * 8);
          acc[mt] = __builtin_amdgcn_mfma_f32_16x16x32_f16(af, wf[kx][cc], acc[mt], 0, 0, 0);
        }
      }
    }
  }

  const int c = c0 + lr;
  #pragma unroll
  for (int mt = 0; mt < 5; mt++) {
    #pragma unroll
    for (int r = 0; r < 4; r++) {
      int f = mt * 16 + lg * 4 + r;
      out[((size_t)(b * TDIM + t) * FDIM + f) * 64 + c] = acc[mt][r];
    }
  }
}

extern "C" void kernel_launch(void* const* d_in, const int* in_sizes, int n_in,
                              void* d_out, int out_size, void* d_ws, size_t ws_size,
                              hipStream_t stream)
{
  const float* q  = (const float*)d_in[0];
  const float* k  = (const float*)d_in[1];
  const float* v  = (const float*)d_in[2];
  const float* wq = (const float*)d_in[3];
  const float* bq = (const float*)d_in[4];
  const float* wk = (const float*)d_in[5];
  const float* bk = (const float*)d_in[6];
  const float* wv = (const float*)d_in[7];
  const float* bv = (const float*)d_in[8];
  const float* wo = (const float*)d_in[9];
  const float* bo = (const float*)d_in[10];

  const size_t PLANE = (size_t)8 * 64 * 512 * 80;   // 20,971,520 elements
  __half* XQh  = (__half*)d_ws;
  __half* XKh  = XQh + PLANE;
  __half* CATh = XKh + PLANE;                       // [B,T,F,128] fp16
  __half* XVh  = (__half*)d_out;                    // dead before k_conv_out writes

  hipLaunchKernelGGL(k_conv_in, dim3(4096), dim3(256), 0, stream, q, wq, bq, XQh);
  hipLaunchKernelGGL(k_conv_in, dim3(4096), dim3(256), 0, stream, k, wk, bk, XKh);
  hipLaunchKernelGGL(k_conv_in, dim3(4096), dim3(256), 0, stream, v, wv, bv, XVh);
  hipLaunchKernelGGL(k_attn_freq, dim3(4096), dim3(256), 0, stream, XQh, XKh, XVh, CATh);
  hipLaunchKernelGGL(k_attn_time, dim3(512), dim3(256), 0, stream, XQh, XKh, XVh, CATh);
  hipLaunchKernelGGL(k_conv_out, dim3(4096), dim3(256), 0, stream, CATh, wo, bo, (float*)d_out);
}

// Round 8
// 803.828 us; speedup vs baseline: 4.7388x; 1.0196x over previous
//
#include <hip/hip_runtime.h>
#include <hip/hip_fp16.h>

#define TDIM 512
#define FDIM 80

typedef _Float16 f16x8 __attribute__((ext_vector_type(8)));
typedef _Float16 f16x4 __attribute__((ext_vector_type(4)));
typedef _Float16 f16x2 __attribute__((ext_vector_type(2)));
typedef float f32x4 __attribute__((ext_vector_type(4)));

// ---------------- conv 3x3 64->64 via MFMA: in NHWC [B,T,F,64] fp32, out [B,C,T,F] fp16 ----------------
__global__ __launch_bounds__(256) void k_conv_in(
    const float* __restrict__ x, const float* __restrict__ w,
    const float* __restrict__ bias, __half* __restrict__ y)
{
  __shared__ __align__(16) _Float16 xs[246 * 72];  // [ky*82+fi][ci], fi = f+1, stride 72
  const int bid = blockIdx.x;
  const int b = bid >> 9, t = bid & 511;
  const int tid = threadIdx.x;
  const int wv = tid >> 6, ln = tid & 63;
  const int lr = ln & 15, lg = ln >> 4;
  const int c0 = wv * 16;

  for (int idx = tid; idx < 246 * 16; idx += 256) {
    int r2 = idx >> 4, cq = idx & 15;
    int ky = r2 / 82, fi = r2 - ky * 82;
    int tt = t + ky - 1, ff = fi - 1;
    f16x4 h;
    #pragma unroll
    for (int j = 0; j < 4; j++) h[j] = (_Float16)0.f;
    if (tt >= 0 && tt < TDIM && ff >= 0 && ff < FDIM) {
      float4 v = *reinterpret_cast<const float4*>(x + (((b * TDIM + tt) * FDIM + ff) << 6) + cq * 4);
      h[0] = (_Float16)v.x; h[1] = (_Float16)v.y; h[2] = (_Float16)v.z; h[3] = (_Float16)v.w;
    }
    *reinterpret_cast<f16x4*>(&xs[r2 * 72 + cq * 4]) = h;
  }
  __syncthreads();

  float bv = bias[c0 + lr];
  f32x4 acc[5];
  #pragma unroll
  for (int mt = 0; mt < 5; mt++)
    #pragma unroll
    for (int r = 0; r < 4; r++) acc[mt][r] = bv;

  for (int ky = 0; ky < 3; ky++) {
    f16x8 wf[3][2];
    #pragma unroll
    for (int kx = 0; kx < 3; kx++)
      #pragma unroll
      for (int cc = 0; cc < 2; cc++) {
        const float* wp = w + ((ky * 3 + kx) * 64 + cc * 32 + lg * 8) * 64 + c0 + lr;
        #pragma unroll
        for (int j = 0; j < 8; j++) wf[kx][cc][j] = (_Float16)wp[j * 64];
      }
    #pragma unroll
    for (int mt = 0; mt < 5; mt++) {
      #pragma unroll
      for (int kx = 0; kx < 3; kx++) {
        const _Float16* ap = &xs[(ky * 82 + mt * 16 + lr + kx) * 72];
        #pragma unroll
        for (int cc = 0; cc < 2; cc++) {
          f16x8 af = *reinterpret_cast<const f16x8*>(ap + cc * 32 + lg * 8);
          acc[mt] = __builtin_amdgcn_mfma_f32_16x16x32_f16(af, wf[kx][cc], acc[mt], 0, 0, 0);
        }
      }
    }
  }

  const int c = c0 + lr;
  #pragma unroll
  for (int mt = 0; mt < 5; mt++) {
    int f0 = mt * 16 + lg * 4;
    f16x4 h;
    #pragma unroll
    for (int r = 0; r < 4; r++) h[r] = (_Float16)acc[mt][r];
    *reinterpret_cast<f16x4*>(y + ((size_t)(b * 64 + c) * TDIM + t) * FDIM + f0) = h;
  }
}

// ---------------- freq attention (MFMA, KVBLK=64, reg-prefetch, L2-chunked remap) ----------------
__global__ __launch_bounds__(256) void k_attn_freq(
    const __half* __restrict__ XQ, const __half* __restrict__ XK,
    const __half* __restrict__ XV, __half* __restrict__ CAT)
{
  __shared__ __align__(16) _Float16 Ks[64 * 104];   // [m][k], cols 80..103 pad (zeroed once)
  __shared__ __align__(16) _Float16 Vt[80 * 72];    // [f][m] transposed V, stride 72
  __shared__ __align__(16) _Float16 Pl[4 * 16 * 72];// per-wave P bounce [16 q][72]

  const int bid = blockIdx.x;
  // bijective remap: per-XCD processing order chunks bc's so 8 bc x 8 tl co-reside (1.3MB < L2)
  const int x8 = bid & 7, kk = bid >> 3;
  const int cc8 = kk >> 6, tl = (kk >> 3) & 7, jj = kk & 7;
  const int bc = x8 + cc8 * 64 + jj * 8;            // bc % 8 == x8 (XCD-stable)
  const int b = bc >> 6, c = bc & 63;
  const int t0 = tl * 64;
  const int tid = threadIdx.x;
  const int wv = tid >> 6, ln = tid & 63;
  const int lr = ln & 15, lg = ln >> 4;
  const float qscale = 0.1118033988749895f;         // 1/sqrt(80)

  const _Float16* Qg = (const _Float16*)XQ + (size_t)bc * 40960 + (size_t)t0 * 80;
  const _Float16* Kg = (const _Float16*)XK + (size_t)bc * 40960;
  const _Float16* Vg = (const _Float16*)XV + (size_t)bc * 40960;

  f16x8 qf[3];
  qf[0] = *reinterpret_cast<const f16x8*>(Qg + (wv * 16 + lr) * 80 + lg * 8);
  qf[1] = *reinterpret_cast<const f16x8*>(Qg + (wv * 16 + lr) * 80 + 32 + lg * 8);
  {
    f16x8 z;
    #pragma unroll
    for (int j = 0; j < 8; j++) z[j] = (_Float16)0.f;
    qf[2] = (lg < 2) ? *reinterpret_cast<const f16x8*>(Qg + (wv * 16 + lr) * 80 + 64 + lg * 8) : z;
  }

  for (int idx = tid; idx < 192; idx += 256) {      // zero K pad cols 80..103
    int row = idx / 3, cw = idx - row * 3;
    f16x8 z;
    #pragma unroll
    for (int j = 0; j < 8; j++) z[j] = (_Float16)0.f;
    *reinterpret_cast<f16x8*>(&Ks[row * 104 + 80 + cw * 8]) = z;
  }

  // K tile: 640 f16x8 chunks (i = tid, tid+256, tid+512<128)
  // V tile: lane owns row vm = tid&63; loads f16x4 at f4 = (tid>>6) + 4s, s=0..4
  const int vm = tid & 63;
  f16x8 kreg0, kreg1, kreg2;
  f16x4 vreg[5];
  {
    int i0 = tid, r0 = i0 / 10, w0 = i0 - r0 * 10;
    kreg0 = *reinterpret_cast<const f16x8*>(Kg + r0 * 80 + w0 * 8);
    int i1 = tid + 256, r1 = i1 / 10, w1 = i1 - r1 * 10;
    kreg1 = *reinterpret_cast<const f16x8*>(Kg + r1 * 80 + w1 * 8);
    if (tid < 128) {
      int i2 = tid + 512, r2 = i2 / 10, w2 = i2 - r2 * 10;
      kreg2 = *reinterpret_cast<const f16x8*>(Kg + r2 * 80 + w2 * 8);
    }
    #pragma unroll
    for (int s = 0; s < 5; s++)
      vreg[s] = *reinterpret_cast<const f16x4*>(Vg + vm * 80 + (wv + 4 * s) * 4);
  }

  f32x4 O[5];
  #pragma unroll
  for (int ft = 0; ft < 5; ft++)
    #pragma unroll
    for (int r = 0; r < 4; r++) O[ft][r] = 0.f;
  float m_r[4], l_r[4];
  #pragma unroll
  for (int r = 0; r < 4; r++) { m_r[r] = -1e30f; l_r[r] = 0.f; }

  for (int kt = 0; kt < 8; kt++) {
    __syncthreads();
    {
      int i0 = tid, r0 = i0 / 10, w0 = i0 - r0 * 10;
      *reinterpret_cast<f16x8*>(&Ks[r0 * 104 + w0 * 8]) = kreg0;
      int i1 = tid + 256, r1 = i1 / 10, w1 = i1 - r1 * 10;
      *reinterpret_cast<f16x8*>(&Ks[r1 * 104 + w1 * 8]) = kreg1;
      if (tid < 128) {
        int i2 = tid + 512, r2 = i2 / 10, w2 = i2 - r2 * 10;
        *reinterpret_cast<f16x8*>(&Ks[r2 * 104 + w2 * 8]) = kreg2;
      }
      // V^T scatter: per store instr, 64 lanes (vm=0..63) hit 32 dwords -> conflict-free
      #pragma unroll
      for (int s = 0; s < 5; s++) {
        int f4 = wv + 4 * s;
        #pragma unroll
        for (int e = 0; e < 4; e++)
          Vt[(f4 * 4 + e) * 72 + vm] = vreg[s][e];
      }
    }
    if (kt < 7) {
      const _Float16* Kn = Kg + (kt + 1) * 64 * 80;
      const _Float16* Vn = Vg + (kt + 1) * 64 * 80;
      int i0 = tid, r0 = i0 / 10, w0 = i0 - r0 * 10;
      kreg0 = *reinterpret_cast<const f16x8*>(Kn + r0 * 80 + w0 * 8);
      int i1 = tid + 256, r1 = i1 / 10, w1 = i1 - r1 * 10;
      kreg1 = *reinterpret_cast<const f16x8*>(Kn + r1 * 80 + w1 * 8);
      if (tid < 128) {
        int i2 = tid + 512, r2 = i2 / 10, w2 = i2 - r2 * 10;
        kreg2 = *reinterpret_cast<const f16x8*>(Kn + r2 * 80 + w2 * 8);
      }
      #pragma unroll
      for (int s = 0; s < 5; s++)
        vreg[s] = *reinterpret_cast<const f16x4*>(Vn + vm * 80 + (wv + 4 * s) * 4);
    }
    __syncthreads();

    // ---- QK^T: S[16 q][64 m] per wave (12 MFMAs)
    f32x4 S[4];
    #pragma unroll
    for (int ms = 0; ms < 4; ms++)
      #pragma unroll
      for (int r = 0; r < 4; r++) S[ms][r] = 0.f;
    __builtin_amdgcn_s_setprio(1);
    #pragma unroll
    for (int kc = 0; kc < 3; kc++) {
      #pragma unroll
      for (int ms = 0; ms < 4; ms++) {
        f16x8 kf = *reinterpret_cast<const f16x8*>(&Ks[(ms * 16 + lr) * 104 + kc * 32 + lg * 8]);
        S[ms] = __builtin_amdgcn_mfma_f32_16x16x32_f16(qf[kc], kf, S[ms], 0, 0, 0);
      }
    }
    __builtin_amdgcn_s_setprio(0);

    // ---- online softmax (row q = lg*4+r, cols m = ms*16+lr)
    float p[4][4], corr[4];
    #pragma unroll
    for (int r = 0; r < 4; r++) {
      float s0 = S[0][r] * qscale, s1 = S[1][r] * qscale;
      float s2 = S[2][r] * qscale, s3 = S[3][r] * qscale;
      float tm = fmaxf(fmaxf(s0, s1), fmaxf(s2, s3));
      tm = fmaxf(tm, __shfl_xor(tm, 1, 16));
      tm = fmaxf(tm, __shfl_xor(tm, 2, 16));
      tm = fmaxf(tm, __shfl_xor(tm, 4, 16));
      tm = fmaxf(tm, __shfl_xor(tm, 8, 16));
      float mn = fmaxf(m_r[r], tm);
      corr[r] = __expf(m_r[r] - mn);
      m_r[r] = mn;
      p[0][r] = __expf(s0 - mn); p[1][r] = __expf(s1 - mn);
      p[2][r] = __expf(s2 - mn); p[3][r] = __expf(s3 - mn);
      float ls = (p[0][r] + p[1][r]) + (p[2][r] + p[3][r]);
      ls += __shfl_xor(ls, 1, 16);
      ls += __shfl_xor(ls, 2, 16);
      ls += __shfl_xor(ls, 4, 16);
      ls += __shfl_xor(ls, 8, 16);
      l_r[r] = l_r[r] * corr[r] + ls;
    }
    #pragma unroll
    for (int ft = 0; ft < 5; ft++)
      #pragma unroll
      for (int r = 0; r < 4; r++) O[ft][r] *= corr[r];

    // ---- P (C-layout) -> wave-private LDS -> A-layout fragments
    _Float16* pw = &Pl[wv * 16 * 72];
    #pragma unroll
    for (int r = 0; r < 4; r++) {
      int row = lg * 4 + r;
      #pragma unroll
      for (int ms = 0; ms < 4; ms++)
        pw[row * 72 + ms * 16 + lr] = (_Float16)p[ms][r];
    }
    asm volatile("s_waitcnt lgkmcnt(0)" ::: "memory");
    f16x8 pf0 = *reinterpret_cast<const f16x8*>(&pw[lr * 72 + lg * 8]);
    f16x8 pf1 = *reinterpret_cast<const f16x8*>(&pw[lr * 72 + 32 + lg * 8]);

    // ---- PV: O[16 q][80 f] += P(16x64) * V(64x80)  (10 MFMAs)
    __builtin_amdgcn_s_setprio(1);
    #pragma unroll
    for (int ft = 0; ft < 5; ft++) {
      f16x8 vf0 = *reinterpret_cast<const f16x8*>(&Vt[(ft * 16 + lr) * 72 + lg * 8]);
      f16x8 vf1 = *reinterpret_cast<const f16x8*>(&Vt[(ft * 16 + lr) * 72 + 32 + lg * 8]);
      O[ft] = __builtin_amdgcn_mfma_f32_16x16x32_f16(pf0, vf0, O[ft], 0, 0, 0);
      O[ft] = __builtin_amdgcn_mfma_f32_16x16x32_f16(pf1, vf1, O[ft], 0, 0, 0);
    }
    __builtin_amdgcn_s_setprio(0);
  }

  #pragma unroll
  for (int r = 0; r < 4; r++) {
    float inv = 1.f / l_r[r];
    int t = t0 + wv * 16 + lg * 4 + r;
    size_t base = (((size_t)b * TDIM + t) * FDIM) * 128 + 64 + c;
    #pragma unroll
    for (int ft = 0; ft < 5; ft++) {
      int f = ft * 16 + lr;
      CAT[base + (size_t)f * 128] = __float2half(O[ft][r] * inv);
    }
  }
}

// ---------------- time attention via MFMA: per (b,c); S=Q^T K (K-dim t=512), then PV ----------------
__global__ __launch_bounds__(256) void k_attn_time(
    const __half* __restrict__ XQ, const __half* __restrict__ XK,
    const __half* __restrict__ XV, __half* __restrict__ CAT)
{
  __shared__ __align__(16) char smem[70400];
  _Float16* Qt  = (_Float16*)smem;              // [80][136] phase1
  _Float16* Kt  = Qt + 80 * 136;                // [80][136]
  float*    Sld = (float*)(smem + 43520);       // [80][84] fp32 scores
  _Float16* Pld = (_Float16*)smem;              // [80][104] phase2 (aliases Qt, post-barrier)

  const int bid = blockIdx.x;                   // 512 blocks = (b,c)
  const int b = bid >> 6, c = bid & 63;
  const int tid = threadIdx.x;
  const int wv = tid >> 6, ln = tid & 63;
  const int lr = ln & 15, lg = ln >> 4;
  const float tscale = 0.04419417382415922f;    // 1/sqrt(512)

  const _Float16* Qg = (const _Float16*)XQ + (size_t)bid * 40960;
  const _Float16* Kg = (const _Float16*)XK + (size_t)bid * 40960;
  const _Float16* Vg = (const _Float16*)XV + (size_t)bid * 40960;

  f32x4 sacc[7];
  #pragma unroll
  for (int i = 0; i < 7; i++)
    #pragma unroll
    for (int r = 0; r < 4; r++) sacc[i][r] = 0.f;

  for (int tc = 0; tc < 4; tc++) {
    __syncthreads();
    for (int idx = tid; idx < 640; idx += 256) {
      int t2 = idx / 10, f8 = idx - t2 * 10;
      int tg = tc * 128 + t2 * 2;
      f16x8 qa = *reinterpret_cast<const f16x8*>(Qg + (size_t)tg * 80 + f8 * 8);
      f16x8 qb = *reinterpret_cast<const f16x8*>(Qg + (size_t)(tg + 1) * 80 + f8 * 8);
      f16x8 ka = *reinterpret_cast<const f16x8*>(Kg + (size_t)tg * 80 + f8 * 8);
      f16x8 kb = *reinterpret_cast<const f16x8*>(Kg + (size_t)(tg + 1) * 80 + f8 * 8);
      #pragma unroll
      for (int j = 0; j < 8; j++) {
        int f = f8 * 8 + j;
        f16x2 qp; qp[0] = qa[j]; qp[1] = qb[j];
        f16x2 kp; kp[0] = ka[j]; kp[1] = kb[j];
        *reinterpret_cast<f16x2*>(&Qt[f * 136 + t2 * 2]) = qp;
        *reinterpret_cast<f16x2*>(&Kt[f * 136 + t2 * 2]) = kp;
      }
    }
    __syncthreads();
    #pragma unroll
    for (int i = 0; i < 7; i++) {
      int ti = wv * 7 + i;
      int te = ti < 25 ? ti : 24;
      int mi = te / 5, ni = te - mi * 5;
      #pragma unroll
      for (int kc = 0; kc < 4; kc++) {
        f16x8 aq = *reinterpret_cast<const f16x8*>(&Qt[(mi * 16 + lr) * 136 + kc * 32 + lg * 8]);
        f16x8 bk = *reinterpret_cast<const f16x8*>(&Kt[(ni * 16 + lr) * 136 + kc * 32 + lg * 8]);
        sacc[i] = __builtin_amdgcn_mfma_f32_16x16x32_f16(aq, bk, sacc[i], 0, 0, 0);
      }
    }
  }
  #pragma unroll
  for (int i = 0; i < 7; i++) {
    int ti = wv * 7 + i;
    if (ti < 25) {
      int mi = ti / 5, ni = ti - mi * 5;
      #pragma unroll
      for (int r = 0; r < 4; r++)
        Sld[(mi * 16 + lg * 4 + r) * 84 + ni * 16 + lr] = sacc[i][r] * tscale;
    }
  }
  __syncthreads();

  {
    const int fy = tid >> 4, gx = tid & 15;
    #pragma unroll
    for (int pass = 0; pass < 5; pass++) {
      int row = pass * 16 + fy;
      float s[5];
      #pragma unroll
      for (int j = 0; j < 5; j++) s[j] = Sld[row * 84 + gx + 16 * j];
      float mx = fmaxf(fmaxf(fmaxf(s[0], s[1]), fmaxf(s[2], s[3])), s[4]);
      #pragma unroll
      for (int sh = 1; sh < 16; sh <<= 1) mx = fmaxf(mx, __shfl_xor(mx, sh, 16));
      float e[5]; float ls = 0.f;
      #pragma unroll
      for (int j = 0; j < 5; j++) { e[j] = __expf(s[j] - mx); ls += e[j]; }
      #pragma unroll
      for (int sh = 1; sh < 16; sh <<= 1) ls += __shfl_xor(ls, sh, 16);
      float inv = 1.f / ls;
      #pragma unroll
      for (int j = 0; j < 5; j++)
        Pld[row * 104 + gx + 16 * j] = (_Float16)(e[j] * inv);
    }
    for (int idx = tid; idx < 240; idx += 256) {
      int row = idx / 3, cw = idx - row * 3;
      f16x8 z;
      #pragma unroll
      for (int j = 0; j < 8; j++) z[j] = (_Float16)0.f;
      *reinterpret_cast<f16x8*>(&Pld[row * 104 + 80 + cw * 8]) = z;
    }
  }
  __syncthreads();

  f16x8 pa[5][3];
  #pragma unroll
  for (int mi = 0; mi < 5; mi++)
    #pragma unroll
    for (int kc = 0; kc < 3; kc++)
      pa[mi][kc] = *reinterpret_cast<const f16x8*>(&Pld[(mi * 16 + lr) * 104 + kc * 32 + lg * 8]);

  #pragma unroll
  for (int j = 0; j < 8; j++) {
    int nt = wv * 8 + j;
    f16x8 vf[3];
    #pragma unroll
    for (int kc = 0; kc < 3; kc++) {
      if (kc < 2) {
        vf[kc] = *reinterpret_cast<const f16x8*>(Vg + (size_t)(nt * 16 + lr) * 80 + kc * 32 + lg * 8);
      } else {
        f16x8 z;
        #pragma unroll
        for (int q = 0; q < 8; q++) z[q] = (_Float16)0.f;
        vf[kc] = (lg < 2) ? *reinterpret_cast<const f16x8*>(Vg + (size_t)(nt * 16 + lr) * 80 + 64 + lg * 8) : z;
      }
    }
    f32x4 oacc[5];
    #pragma unroll
    for (int mi = 0; mi < 5; mi++)
      #pragma unroll
      for (int r = 0; r < 4; r++) oacc[mi][r] = 0.f;
    #pragma unroll
    for (int mi = 0; mi < 5; mi++)
      #pragma unroll
      for (int kc = 0; kc < 3; kc++)
        oacc[mi] = __builtin_amdgcn_mfma_f32_16x16x32_f16(pa[mi][kc], vf[kc], oacc[mi], 0, 0, 0);

    int t = nt * 16 + lr;
    size_t base = (((size_t)b * TDIM + t) * FDIM) * 128 + c;
    #pragma unroll
    for (int mi = 0; mi < 5; mi++)
      #pragma unroll
      for (int r = 0; r < 4; r++) {
        int f = mi * 16 + lg * 4 + r;
        CAT[base + (size_t)f * 128] = __float2half(oacc[mi][r]);
      }
  }
}

// ---------------- conv 3x3 128->64 via MFMA: in [B,T,F,128] fp16 (CAT), out NHWC [B,T,F,64] fp32 ----------------
__global__ __launch_bounds__(256) void k_conv_out(
    const __half* __restrict__ x, const float* __restrict__ w,
    const float* __restrict__ bias, float* __restrict__ out)
{
  __shared__ __align__(16) _Float16 xs[246 * 136];
  const int bid = blockIdx.x;
  const int b = bid >> 9, t = bid & 511;
  const int tid = threadIdx.x;
  const int wv = tid >> 6, ln = tid & 63;
  const int lr = ln & 15, lg = ln >> 4;
  const int c0 = wv * 16;

  for (int idx = tid; idx < 246 * 16; idx += 256) {
    int r2 = idx >> 4, cq = idx & 15;
    int ky = r2 / 82, fi = r2 - ky * 82;
    int tt = t + ky - 1, ff = fi - 1;
    f16x8 h;
    #pragma unroll
    for (int j = 0; j < 8; j++) h[j] = (_Float16)0.f;
    if (tt >= 0 && tt < TDIM && ff >= 0 && ff < FDIM)
      h = *reinterpret_cast<const f16x8*>(x + (((size_t)(b * TDIM + tt) * FDIM + ff) << 7) + cq * 8);
    *reinterpret_cast<f16x8*>(&xs[r2 * 136 + cq * 8]) = h;
  }
  __syncthreads();

  float bv = bias[c0 + lr];
  f32x4 acc[5];
  #pragma unroll
  for (int mt = 0; mt < 5; mt++)
    #pragma unroll
    for (int r = 0; r < 4; r++) acc[mt][r] = bv;

  for (int ky = 0; ky < 3; ky++) {
    f16x8 wf[3][4];
    #pragma unroll
    for (int kx = 0; kx < 3; kx++)
      #pragma unroll
      for (int cc = 0; cc < 4; cc++) {
        const float* wp = w + ((ky * 3 + kx) * 128 + cc * 32 + lg * 8) * 64 + c0 + lr;
        #pragma unroll
        for (int j = 0; j < 8; j++) wf[kx][cc][j] = (_Float16)wp[j * 64];
      }
    #pragma unroll
    for (int mt = 0; mt < 5; mt++) {
      #pragma unroll
      for (int kx = 0; kx < 3; kx++) {
        const _Float16* ap = &xs[(ky * 82 + mt * 16 + lr + kx) * 136];
        #pragma unroll
        for (int cc = 0; cc < 4; cc++) {
          f16x8 af = *reinterpret_cast<const f16x8*>(ap + cc * 32 + lg * 8);
          acc[mt] = __builtin_amdgcn_mfma_f32_16x16x32_f16(af, wf[kx][cc], acc[mt], 0, 0, 0);
        }
      }
    }
  }

  const int c = c0 + lr;
  #pragma unroll
  for (int mt = 0; mt < 5; mt++) {
    #pragma unroll
    for (int r = 0; r < 4; r++) {
      int f = mt * 16 + lg * 4 + r;
      out[((size_t)(b * TDIM + t) * FDIM + f) * 64 + c] = acc[mt][r];
    }
  }
}

extern "C" void kernel_launch(void* const* d_in, const int* in_sizes, int n_in,
                              void* d_out, int out_size, void* d_ws, size_t ws_size,
                              hipStream_t stream)
{
  const float* q  = (const float*)d_in[0];
  const float* k  = (const float*)d_in[1];
  const float* v  = (const float*)d_in[2];
  const float* wq = (const float*)d_in[3];
  const float* bq = (const float*)d_in[4];
  const float* wk = (const float*)d_in[5];
  const float* bk = (const float*)d_in[6];
  const float* wv = (const float*)d_in[7];
  const float* bv = (const float*)d_in[8];
  const float* wo = (const float*)d_in[9];
  const float* bo = (const float*)d_in[10];

  const size_t PLANE = (size_t)8 * 64 * 512 * 80;   // 20,971,520 elements
  __half* XQh  = (__half*)d_ws;
  __half* XKh  = XQh + PLANE;
  __half* CATh = XKh + PLANE;                       // [B,T,F,128] fp16
  __half* XVh  = (__half*)d_out;                    // dead before k_conv_out writes

  hipLaunchKernelGGL(k_conv_in, dim3(4096), dim3(256), 0, stream, q, wq, bq, XQh);
  hipLaunchKernelGGL(k_conv_in, dim3(4096), dim3(256), 0, stream, k, wk, bk, XKh);
  hipLaunchKernelGGL(k_conv_in, dim3(4096), dim3(256), 0, stream, v, wv, bv, XVh);
  hipLaunchKernelGGL(k_attn_freq, dim3(4096), dim3(256), 0, stream, XQh, XKh, XVh, CATh);
  hipLaunchKernelGGL(k_attn_time, dim3(512), dim3(256), 0, stream, XQh, XKh, XVh, CATh);
  hipLaunchKernelGGL(k_conv_out, dim3(4096), dim3(256), 0, stream, CATh, wo, bo, (float*)d_out);
}

// Round 9
// 519.635 us; speedup vs baseline: 7.3305x; 1.5469x over previous
//
#include <hip/hip_runtime.h>
#include <hip/hip_fp16.h>

#define TDIM 512
#define FDIM 80

typedef _Float16 f16x8 __attribute__((ext_vector_type(8)));
typedef _Float16 f16x4 __attribute__((ext_vector_type(4)));
typedef _Float16 f16x2 __attribute__((ext_vector_type(2)));
typedef float f32x4 __attribute__((ext_vector_type(4)));

// ---------------- conv 3x3 64->64 via MFMA: in NHWC [B,T,F,64] fp32, out [B,C,T,F] fp16 ----------------
__global__ __launch_bounds__(256) void k_conv_in(
    const float* __restrict__ x, const float* __restrict__ w,
    const float* __restrict__ bias, _Float16* __restrict__ y)
{
  __shared__ __align__(16) _Float16 xs[246 * 72];  // [ky*82+fi][ci], fi = f+1, stride 72
  const int bid = blockIdx.x;
  const int b = bid >> 9, t = bid & 511;
  const int tid = threadIdx.x;
  const int wv = tid >> 6, ln = tid & 63;
  const int lr = ln & 15, lg = ln >> 4;
  const int c0 = wv * 16;

  for (int idx = tid; idx < 246 * 16; idx += 256) {
    int r2 = idx >> 4, cq = idx & 15;
    int ky = r2 / 82, fi = r2 - ky * 82;
    int tt = t + ky - 1, ff = fi - 1;
    f16x4 h;
    #pragma unroll
    for (int j = 0; j < 4; j++) h[j] = (_Float16)0.f;
    if (tt >= 0 && tt < TDIM && ff >= 0 && ff < FDIM) {
      float4 v = *reinterpret_cast<const float4*>(x + (((b * TDIM + tt) * FDIM + ff) << 6) + cq * 4);
      h[0] = (_Float16)v.x; h[1] = (_Float16)v.y; h[2] = (_Float16)v.z; h[3] = (_Float16)v.w;
    }
    *reinterpret_cast<f16x4*>(&xs[r2 * 72 + cq * 4]) = h;
  }
  __syncthreads();

  float bv = bias[c0 + lr];
  f32x4 acc[5];
  #pragma unroll
  for (int mt = 0; mt < 5; mt++)
    #pragma unroll
    for (int r = 0; r < 4; r++) acc[mt][r] = bv;

  for (int ky = 0; ky < 3; ky++) {
    f16x8 wf[3][2];
    #pragma unroll
    for (int kx = 0; kx < 3; kx++)
      #pragma unroll
      for (int cc = 0; cc < 2; cc++) {
        const float* wp = w + ((ky * 3 + kx) * 64 + cc * 32 + lg * 8) * 64 + c0 + lr;
        #pragma unroll
        for (int j = 0; j < 8; j++) wf[kx][cc][j] = (_Float16)wp[j * 64];
      }
    #pragma unroll
    for (int mt = 0; mt < 5; mt++) {
      #pragma unroll
      for (int kx = 0; kx < 3; kx++) {
        const _Float16* ap = &xs[(ky * 82 + mt * 16 + lr + kx) * 72];
        #pragma unroll
        for (int cc = 0; cc < 2; cc++) {
          f16x8 af = *reinterpret_cast<const f16x8*>(ap + cc * 32 + lg * 8);
          acc[mt] = __builtin_amdgcn_mfma_f32_16x16x32_f16(af, wf[kx][cc], acc[mt], 0, 0, 0);
        }
      }
    }
  }

  // epilogue: bounce [64 c][80 f] through LDS (alias xs), then coalesced f16x8 rows
  __syncthreads();                   // all waves done reading xs
  _Float16* yt = xs;                 // [64 c][88 f]
  const int c = c0 + lr;
  #pragma unroll
  for (int mt = 0; mt < 5; mt++) {
    f16x4 h;
    #pragma unroll
    for (int r = 0; r < 4; r++) h[r] = (_Float16)acc[mt][r];
    *reinterpret_cast<f16x4*>(&yt[c * 88 + mt * 16 + lg * 4]) = h;
  }
  __syncthreads();
  #pragma unroll
  for (int k = 0; k < 3; k++) {
    int idx = tid + (k << 8);
    if (idx < 640) {
      int cc = idx / 10, f8 = idx - cc * 10;
      *reinterpret_cast<f16x8*>(y + ((size_t)(b * 64 + cc) * TDIM + t) * FDIM + f8 * 8) =
          *reinterpret_cast<const f16x8*>(&yt[cc * 88 + f8 * 8]);
    }
  }
}

// ---------------- freq attention (MFMA, KVBLK=64, reg-prefetch, L2-chunked remap) ----------------
// CAT2 layout: [B][128][T][F]; freq writes channels 64..127 (its own contiguous plane)
__global__ __launch_bounds__(256) void k_attn_freq(
    const _Float16* __restrict__ XQ, const _Float16* __restrict__ XK,
    const _Float16* __restrict__ XV, _Float16* __restrict__ CAT)
{
  __shared__ __align__(16) _Float16 Ks[64 * 104];   // [m][k], cols 80..103 pad (zeroed once)
  __shared__ __align__(16) _Float16 Vt[80 * 72];    // [f][m] transposed V, stride 72
  __shared__ __align__(16) _Float16 Pl[4 * 16 * 72];// per-wave P bounce [16 q][72]

  const int bid = blockIdx.x;
  const int x8 = bid & 7, kk = bid >> 3;
  const int cc8 = kk >> 6, tl = (kk >> 3) & 7, jj = kk & 7;
  const int bc = x8 + cc8 * 64 + jj * 8;            // bc % 8 == x8 (XCD-stable)
  const int b = bc >> 6, c = bc & 63;
  const int t0 = tl * 64;
  const int tid = threadIdx.x;
  const int wv = tid >> 6, ln = tid & 63;
  const int lr = ln & 15, lg = ln >> 4;
  const float qscale = 0.1118033988749895f;         // 1/sqrt(80)

  const _Float16* Qg = XQ + (size_t)bc * 40960 + (size_t)t0 * 80;
  const _Float16* Kg = XK + (size_t)bc * 40960;
  const _Float16* Vg = XV + (size_t)bc * 40960;

  f16x8 qf[3];
  qf[0] = *reinterpret_cast<const f16x8*>(Qg + (wv * 16 + lr) * 80 + lg * 8);
  qf[1] = *reinterpret_cast<const f16x8*>(Qg + (wv * 16 + lr) * 80 + 32 + lg * 8);
  {
    f16x8 z;
    #pragma unroll
    for (int j = 0; j < 8; j++) z[j] = (_Float16)0.f;
    qf[2] = (lg < 2) ? *reinterpret_cast<const f16x8*>(Qg + (wv * 16 + lr) * 80 + 64 + lg * 8) : z;
  }

  for (int idx = tid; idx < 192; idx += 256) {      // zero K pad cols 80..103
    int row = idx / 3, cw = idx - row * 3;
    f16x8 z;
    #pragma unroll
    for (int j = 0; j < 8; j++) z[j] = (_Float16)0.f;
    *reinterpret_cast<f16x8*>(&Ks[row * 104 + 80 + cw * 8]) = z;
  }

  const int vm = tid & 63;
  f16x8 kreg0, kreg1, kreg2;
  f16x4 vreg[5];
  {
    int i0 = tid, r0 = i0 / 10, w0 = i0 - r0 * 10;
    kreg0 = *reinterpret_cast<const f16x8*>(Kg + r0 * 80 + w0 * 8);
    int i1 = tid + 256, r1 = i1 / 10, w1 = i1 - r1 * 10;
    kreg1 = *reinterpret_cast<const f16x8*>(Kg + r1 * 80 + w1 * 8);
    if (tid < 128) {
      int i2 = tid + 512, r2 = i2 / 10, w2 = i2 - r2 * 10;
      kreg2 = *reinterpret_cast<const f16x8*>(Kg + r2 * 80 + w2 * 8);
    }
    #pragma unroll
    for (int s = 0; s < 5; s++)
      vreg[s] = *reinterpret_cast<const f16x4*>(Vg + vm * 80 + (wv + 4 * s) * 4);
  }

  f32x4 O[5];
  #pragma unroll
  for (int ft = 0; ft < 5; ft++)
    #pragma unroll
    for (int r = 0; r < 4; r++) O[ft][r] = 0.f;
  float m_r[4], l_r[4];
  #pragma unroll
  for (int r = 0; r < 4; r++) { m_r[r] = -1e30f; l_r[r] = 0.f; }

  for (int kt = 0; kt < 8; kt++) {
    __syncthreads();
    {
      int i0 = tid, r0 = i0 / 10, w0 = i0 - r0 * 10;
      *reinterpret_cast<f16x8*>(&Ks[r0 * 104 + w0 * 8]) = kreg0;
      int i1 = tid + 256, r1 = i1 / 10, w1 = i1 - r1 * 10;
      *reinterpret_cast<f16x8*>(&Ks[r1 * 104 + w1 * 8]) = kreg1;
      if (tid < 128) {
        int i2 = tid + 512, r2 = i2 / 10, w2 = i2 - r2 * 10;
        *reinterpret_cast<f16x8*>(&Ks[r2 * 104 + w2 * 8]) = kreg2;
      }
      #pragma unroll
      for (int s = 0; s < 5; s++) {
        int f4 = wv + 4 * s;
        #pragma unroll
        for (int e = 0; e < 4; e++)
          Vt[(f4 * 4 + e) * 72 + vm] = vreg[s][e];
      }
    }
    if (kt < 7) {
      const _Float16* Kn = Kg + (kt + 1) * 64 * 80;
      const _Float16* Vn = Vg + (kt + 1) * 64 * 80;
      int i0 = tid, r0 = i0 / 10, w0 = i0 - r0 * 10;
      kreg0 = *reinterpret_cast<const f16x8*>(Kn + r0 * 80 + w0 * 8);
      int i1 = tid + 256, r1 = i1 / 10, w1 = i1 - r1 * 10;
      kreg1 = *reinterpret_cast<const f16x8*>(Kn + r1 * 80 + w1 * 8);
      if (tid < 128) {
        int i2 = tid + 512, r2 = i2 / 10, w2 = i2 - r2 * 10;
        kreg2 = *reinterpret_cast<const f16x8*>(Kn + r2 * 80 + w2 * 8);
      }
      #pragma unroll
      for (int s = 0; s < 5; s++)
        vreg[s] = *reinterpret_cast<const f16x4*>(Vn + vm * 80 + (wv + 4 * s) * 4);
    }
    __syncthreads();

    f32x4 S[4];
    #pragma unroll
    for (int ms = 0; ms < 4; ms++)
      #pragma unroll
      for (int r = 0; r < 4; r++) S[ms][r] = 0.f;
    __builtin_amdgcn_s_setprio(1);
    #pragma unroll
    for (int kc = 0; kc < 3; kc++) {
      #pragma unroll
      for (int ms = 0; ms < 4; ms++) {
        f16x8 kf = *reinterpret_cast<const f16x8*>(&Ks[(ms * 16 + lr) * 104 + kc * 32 + lg * 8]);
        S[ms] = __builtin_amdgcn_mfma_f32_16x16x32_f16(qf[kc], kf, S[ms], 0, 0, 0);
      }
    }
    __builtin_amdgcn_s_setprio(0);

    float p[4][4], corr[4];
    #pragma unroll
    for (int r = 0; r < 4; r++) {
      float s0 = S[0][r] * qscale, s1 = S[1][r] * qscale;
      float s2 = S[2][r] * qscale, s3 = S[3][r] * qscale;
      float tm = fmaxf(fmaxf(s0, s1), fmaxf(s2, s3));
      tm = fmaxf(tm, __shfl_xor(tm, 1, 16));
      tm = fmaxf(tm, __shfl_xor(tm, 2, 16));
      tm = fmaxf(tm, __shfl_xor(tm, 4, 16));
      tm = fmaxf(tm, __shfl_xor(tm, 8, 16));
      float mn = fmaxf(m_r[r], tm);
      corr[r] = __expf(m_r[r] - mn);
      m_r[r] = mn;
      p[0][r] = __expf(s0 - mn); p[1][r] = __expf(s1 - mn);
      p[2][r] = __expf(s2 - mn); p[3][r] = __expf(s3 - mn);
      float ls = (p[0][r] + p[1][r]) + (p[2][r] + p[3][r]);
      ls += __shfl_xor(ls, 1, 16);
      ls += __shfl_xor(ls, 2, 16);
      ls += __shfl_xor(ls, 4, 16);
      ls += __shfl_xor(ls, 8, 16);
      l_r[r] = l_r[r] * corr[r] + ls;
    }
    #pragma unroll
    for (int ft = 0; ft < 5; ft++)
      #pragma unroll
      for (int r = 0; r < 4; r++) O[ft][r] *= corr[r];

    _Float16* pw = &Pl[wv * 16 * 72];
    #pragma unroll
    for (int r = 0; r < 4; r++) {
      int row = lg * 4 + r;
      #pragma unroll
      for (int ms = 0; ms < 4; ms++)
        pw[row * 72 + ms * 16 + lr] = (_Float16)p[ms][r];
    }
    asm volatile("s_waitcnt lgkmcnt(0)" ::: "memory");
    f16x8 pf0 = *reinterpret_cast<const f16x8*>(&pw[lr * 72 + lg * 8]);
    f16x8 pf1 = *reinterpret_cast<const f16x8*>(&pw[lr * 72 + 32 + lg * 8]);

    __builtin_amdgcn_s_setprio(1);
    #pragma unroll
    for (int ft = 0; ft < 5; ft++) {
      f16x8 vf0 = *reinterpret_cast<const f16x8*>(&Vt[(ft * 16 + lr) * 72 + lg * 8]);
      f16x8 vf1 = *reinterpret_cast<const f16x8*>(&Vt[(ft * 16 + lr) * 72 + 32 + lg * 8]);
      O[ft] = __builtin_amdgcn_mfma_f32_16x16x32_f16(pf0, vf0, O[ft], 0, 0, 0);
      O[ft] = __builtin_amdgcn_mfma_f32_16x16x32_f16(pf1, vf1, O[ft], 0, 0, 0);
    }
    __builtin_amdgcn_s_setprio(0);
  }

  // epilogue: CAT2 [B][128][T][F], ch = 64+c: contiguous 16-half runs per (ft)
  #pragma unroll
  for (int r = 0; r < 4; r++) {
    float inv = 1.f / l_r[r];
    int t = t0 + wv * 16 + lg * 4 + r;
    size_t base = ((size_t)(b * 128 + 64 + c) * TDIM + t) * FDIM;
    #pragma unroll
    for (int ft = 0; ft < 5; ft++)
      CAT[base + ft * 16 + lr] = (_Float16)(O[ft][r] * inv);
  }
}

// ---------------- time attention via MFMA: per (b,c); writes CAT2 channel c plane ----------------
__global__ __launch_bounds__(256) void k_attn_time(
    const _Float16* __restrict__ XQ, const _Float16* __restrict__ XK,
    const _Float16* __restrict__ XV, _Float16* __restrict__ CAT)
{
  __shared__ __align__(16) char smem[70400];
  _Float16* Qt  = (_Float16*)smem;              // [80][136] phase1
  _Float16* Kt  = Qt + 80 * 136;                // [80][136]
  float*    Sld = (float*)(smem + 43520);       // [80][84] fp32 scores
  _Float16* Pld = (_Float16*)smem;              // [80][104] phase2 (aliases Qt, post-barrier)

  const int bid = blockIdx.x;                   // 512 blocks = (b,c)
  const int b = bid >> 6, c = bid & 63;
  const int tid = threadIdx.x;
  const int wv = tid >> 6, ln = tid & 63;
  const int lr = ln & 15, lg = ln >> 4;
  const float tscale = 0.04419417382415922f;    // 1/sqrt(512)

  const _Float16* Qg = XQ + (size_t)bid * 40960;
  const _Float16* Kg = XK + (size_t)bid * 40960;
  const _Float16* Vg = XV + (size_t)bid * 40960;

  f32x4 sacc[7];
  #pragma unroll
  for (int i = 0; i < 7; i++)
    #pragma unroll
    for (int r = 0; r < 4; r++) sacc[i][r] = 0.f;

  for (int tc = 0; tc < 4; tc++) {
    __syncthreads();
    for (int idx = tid; idx < 640; idx += 256) {
      int t2 = idx / 10, f8 = idx - t2 * 10;
      int tg = tc * 128 + t2 * 2;
      f16x8 qa = *reinterpret_cast<const f16x8*>(Qg + (size_t)tg * 80 + f8 * 8);
      f16x8 qb = *reinterpret_cast<const f16x8*>(Qg + (size_t)(tg + 1) * 80 + f8 * 8);
      f16x8 ka = *reinterpret_cast<const f16x8*>(Kg + (size_t)tg * 80 + f8 * 8);
      f16x8 kb = *reinterpret_cast<const f16x8*>(Kg + (size_t)(tg + 1) * 80 + f8 * 8);
      #pragma unroll
      for (int j = 0; j < 8; j++) {
        int f = f8 * 8 + j;
        f16x2 qp; qp[0] = qa[j]; qp[1] = qb[j];
        f16x2 kp; kp[0] = ka[j]; kp[1] = kb[j];
        *reinterpret_cast<f16x2*>(&Qt[f * 136 + t2 * 2]) = qp;
        *reinterpret_cast<f16x2*>(&Kt[f * 136 + t2 * 2]) = kp;
      }
    }
    __syncthreads();
    #pragma unroll
    for (int i = 0; i < 7; i++) {
      int ti = wv * 7 + i;
      int te = ti < 25 ? ti : 24;
      int mi = te / 5, ni = te - mi * 5;
      #pragma unroll
      for (int kc = 0; kc < 4; kc++) {
        f16x8 aq = *reinterpret_cast<const f16x8*>(&Qt[(mi * 16 + lr) * 136 + kc * 32 + lg * 8]);
        f16x8 bk = *reinterpret_cast<const f16x8*>(&Kt[(ni * 16 + lr) * 136 + kc * 32 + lg * 8]);
        sacc[i] = __builtin_amdgcn_mfma_f32_16x16x32_f16(aq, bk, sacc[i], 0, 0, 0);
      }
    }
  }
  #pragma unroll
  for (int i = 0; i < 7; i++) {
    int ti = wv * 7 + i;
    if (ti < 25) {
      int mi = ti / 5, ni = ti - mi * 5;
      #pragma unroll
      for (int r = 0; r < 4; r++)
        Sld[(mi * 16 + lg * 4 + r) * 84 + ni * 16 + lr] = sacc[i][r] * tscale;
    }
  }
  __syncthreads();

  {
    const int fy = tid >> 4, gx = tid & 15;
    #pragma unroll
    for (int pass = 0; pass < 5; pass++) {
      int row = pass * 16 + fy;
      float s[5];
      #pragma unroll
      for (int j = 0; j < 5; j++) s[j] = Sld[row * 84 + gx + 16 * j];
      float mx = fmaxf(fmaxf(fmaxf(s[0], s[1]), fmaxf(s[2], s[3])), s[4]);
      #pragma unroll
      for (int sh = 1; sh < 16; sh <<= 1) mx = fmaxf(mx, __shfl_xor(mx, sh, 16));
      float e[5]; float ls = 0.f;
      #pragma unroll
      for (int j = 0; j < 5; j++) { e[j] = __expf(s[j] - mx); ls += e[j]; }
      #pragma unroll
      for (int sh = 1; sh < 16; sh <<= 1) ls += __shfl_xor(ls, sh, 16);
      float inv = 1.f / ls;
      #pragma unroll
      for (int j = 0; j < 5; j++)
        Pld[row * 104 + gx + 16 * j] = (_Float16)(e[j] * inv);
    }
    for (int idx = tid; idx < 240; idx += 256) {
      int row = idx / 3, cw = idx - row * 3;
      f16x8 z;
      #pragma unroll
      for (int j = 0; j < 8; j++) z[j] = (_Float16)0.f;
      *reinterpret_cast<f16x8*>(&Pld[row * 104 + 80 + cw * 8]) = z;
    }
  }
  __syncthreads();

  f16x8 pa[5][3];
  #pragma unroll
  for (int mi = 0; mi < 5; mi++)
    #pragma unroll
    for (int kc = 0; kc < 3; kc++)
      pa[mi][kc] = *reinterpret_cast<const f16x8*>(&Pld[(mi * 16 + lr) * 104 + kc * 32 + lg * 8]);

  _Float16* Ow = (_Float16*)(smem + 43520) + wv * (16 * 88);  // per-wave [16 t][88 f] (Sld dead)
  const size_t chbase = (size_t)(b * 128 + c) * TDIM * FDIM;

  #pragma unroll
  for (int j = 0; j < 8; j++) {
    int nt = wv * 8 + j;
    f16x8 vf[3];
    #pragma unroll
    for (int kc = 0; kc < 3; kc++) {
      if (kc < 2) {
        vf[kc] = *reinterpret_cast<const f16x8*>(Vg + (size_t)(nt * 16 + lr) * 80 + kc * 32 + lg * 8);
      } else {
        f16x8 z;
        #pragma unroll
        for (int q = 0; q < 8; q++) z[q] = (_Float16)0.f;
        vf[kc] = (lg < 2) ? *reinterpret_cast<const f16x8*>(Vg + (size_t)(nt * 16 + lr) * 80 + 64 + lg * 8) : z;
      }
    }
    f32x4 oacc[5];
    #pragma unroll
    for (int mi = 0; mi < 5; mi++)
      #pragma unroll
      for (int r = 0; r < 4; r++) oacc[mi][r] = 0.f;
    #pragma unroll
    for (int mi = 0; mi < 5; mi++)
      #pragma unroll
      for (int kc = 0; kc < 3; kc++)
        oacc[mi] = __builtin_amdgcn_mfma_f32_16x16x32_f16(pa[mi][kc], vf[kc], oacc[mi], 0, 0, 0);

    // transpose D-frag (t=nt*16+lr, f=mi*16+lg*4+r) through per-wave LDS, then coalesced rows
    #pragma unroll
    for (int mi = 0; mi < 5; mi++) {
      f16x4 h;
      #pragma unroll
      for (int r = 0; r < 4; r++) h[r] = (_Float16)oacc[mi][r];
      *reinterpret_cast<f16x4*>(&Ow[lr * 88 + mi * 16 + lg * 4]) = h;
    }
    asm volatile("s_waitcnt lgkmcnt(0)" ::: "memory");
    size_t basec = chbase + (size_t)(nt * 16) * FDIM;
    #pragma unroll
    for (int k = 0; k < 3; k++) {
      int idx = ln + (k << 6);
      if (idx < 160) {
        int tl2 = idx / 10, f8 = idx - tl2 * 10;
        *reinterpret_cast<f16x8*>(CAT + basec + tl2 * 80 + f8 * 8) =
            *reinterpret_cast<const f16x8*>(&Ow[tl2 * 88 + f8 * 8]);
      }
    }
  }
}

// ---------------- conv 3x3 128->64 via MFMA: in CAT2 [B][128][T][F] fp16, out NHWC [B,T,F,64] fp32 ----------------
__global__ __launch_bounds__(256) void k_conv_out(
    const _Float16* __restrict__ x, const float* __restrict__ w,
    const float* __restrict__ bias, float* __restrict__ out)
{
  __shared__ __align__(16) _Float16 xs[246 * 136];  // [ky*82+fi][ci], stride 136
  const int bid = blockIdx.x;
  const int b = bid >> 9, t = bid & 511;
  const int tid = threadIdx.x;
  const int wv = tid >> 6, ln = tid & 63;
  const int lr = ln & 15, lg = ln >> 4;
  const int c0 = wv * 16;

  // zero pad columns fi=0 and fi=81
  for (int idx = tid; idx < 768; idx += 256) {
    int cch = idx & 127, sk = idx >> 7;             // sk 0..5
    int ky = sk >> 1, side = sk & 1;
    xs[(ky * 82 + side * 81) * 136 + cch] = (_Float16)0.f;
  }
  // stage from channel-major CAT2: lanes span c (conflict-free LDS), reads via L2
  const _Float16* xb = x + (size_t)b * 128 * TDIM * FDIM;
  #pragma unroll
  for (int k = 0; k < 15; k++) {
    int idx = tid + (k << 8);                       // 0..3839
    int cch = idx & 127, rest = idx >> 7;           // rest 0..29
    int ky = rest / 10, f8 = rest - ky * 10;
    int tt = t + ky - 1;
    f16x8 h;
    #pragma unroll
    for (int j = 0; j < 8; j++) h[j] = (_Float16)0.f;
    if (tt >= 0 && tt < TDIM)
      h = *reinterpret_cast<const f16x8*>(xb + ((size_t)cch * TDIM + tt) * FDIM + f8 * 8);
    #pragma unroll
    for (int j = 0; j < 8; j++)
      xs[(ky * 82 + f8 * 8 + j + 1) * 136 + cch] = h[j];
  }
  __syncthreads();

  float bv = bias[c0 + lr];
  f32x4 acc[5];
  #pragma unroll
  for (int mt = 0; mt < 5; mt++)
    #pragma unroll
    for (int r = 0; r < 4; r++) acc[mt][r] = bv;

  for (int ky = 0; ky < 3; ky++) {
    f16x8 wf[3][4];
    #pragma unroll
    for (int kx = 0; kx < 3; kx++)
      #pragma unroll
      for (int cc = 0; cc < 4; cc++) {
        const float* wp = w + ((ky * 3 + kx) * 128 + cc * 32 + lg * 8) * 64 + c0 + lr;
        #pragma unroll
        for (int j = 0; j < 8; j++) wf[kx][cc][j] = (_Float16)wp[j * 64];
      }
    #pragma unroll
    for (int mt = 0; mt < 5; mt++) {
      #pragma unroll
      for (int kx = 0; kx < 3; kx++) {
        const _Float16* ap = &xs[(ky * 82 + mt * 16 + lr + kx) * 136];
        #pragma unroll
        for (int cc = 0; cc < 4; cc++) {
          f16x8 af = *reinterpret_cast<const f16x8*>(ap + cc * 32 + lg * 8);
          acc[mt] = __builtin_amdgcn_mfma_f32_16x16x32_f16(af, wf[kx][cc], acc[mt], 0, 0, 0);
        }
      }
    }
  }

  const int c = c0 + lr;
  #pragma unroll
  for (int mt = 0; mt < 5; mt++) {
    #pragma unroll
    for (int r = 0; r < 4; r++) {
      int f = mt * 16 + lg * 4 + r;
      out[((size_t)(b * TDIM + t) * FDIM + f) * 64 + c] = acc[mt][r];
    }
  }
}

extern "C" void kernel_launch(void* const* d_in, const int* in_sizes, int n_in,
                              void* d_out, int out_size, void* d_ws, size_t ws_size,
                              hipStream_t stream)
{
  const float* q  = (const float*)d_in[0];
  const float* k  = (const float*)d_in[1];
  const float* v  = (const float*)d_in[2];
  const float* wq = (const float*)d_in[3];
  const float* bq = (const float*)d_in[4];
  const float* wk = (const float*)d_in[5];
  const float* bk = (const float*)d_in[6];
  const float* wv = (const float*)d_in[7];
  const float* bv = (const float*)d_in[8];
  const float* wo = (const float*)d_in[9];
  const float* bo = (const float*)d_in[10];

  const size_t PLANE = (size_t)8 * 64 * 512 * 80;   // 20,971,520 elements
  _Float16* XQh  = (_Float16*)d_ws;
  _Float16* XKh  = XQh + PLANE;
  _Float16* CATh = XKh + PLANE;                     // CAT2 [B][128][T][F] fp16
  _Float16* XVh  = (_Float16*)d_out;                // dead before k_conv_out writes

  hipLaunchKernelGGL(k_conv_in, dim3(4096), dim3(256), 0, stream, q, wq, bq, XQh);
  hipLaunchKernelGGL(k_conv_in, dim3(4096), dim3(256), 0, stream, k, wk, bk, XKh);
  hipLaunchKernelGGL(k_conv_in, dim3(4096), dim3(256), 0, stream, v, wv, bv, XVh);
  hipLaunchKernelGGL(k_attn_freq, dim3(4096), dim3(256), 0, stream, XQh, XKh, XVh, CATh);
  hipLaunchKernelGGL(k_attn_time, dim3(512), dim3(256), 0, stream, XQh, XKh, XVh, CATh);
  hipLaunchKernelGGL(k_conv_out, dim3(4096), dim3(256), 0, stream, CATh, wo, bo, (float*)d_out);
}

// Round 10
// 516.567 us; speedup vs baseline: 7.3740x; 1.0059x over previous
//
#include <hip/hip_runtime.h>
#include <hip/hip_fp16.h>

#define TDIM 512
#define FDIM 80

typedef _Float16 f16x8 __attribute__((ext_vector_type(8)));
typedef _Float16 f16x4 __attribute__((ext_vector_type(4)));
typedef _Float16 f16x2 __attribute__((ext_vector_type(2)));
typedef float f32x4 __attribute__((ext_vector_type(4)));

// ---------------- conv 3x3 64->64 via MFMA: in NHWC [B,T,F,64] fp32, out [B,C,T,F] fp16 ----------------
__global__ __launch_bounds__(256) void k_conv_in(
    const float* __restrict__ x, const float* __restrict__ w,
    const float* __restrict__ bias, _Float16* __restrict__ y)
{
  __shared__ __align__(16) _Float16 xs[246 * 72];  // [ky*82+fi][ci], fi = f+1, stride 72
  const int bid = blockIdx.x;
  const int b = bid >> 9, t = bid & 511;
  const int tid = threadIdx.x;
  const int wv = tid >> 6, ln = tid & 63;
  const int lr = ln & 15, lg = ln >> 4;
  const int c0 = wv * 16;

  for (int idx = tid; idx < 246 * 16; idx += 256) {
    int r2 = idx >> 4, cq = idx & 15;
    int ky = r2 / 82, fi = r2 - ky * 82;
    int tt = t + ky - 1, ff = fi - 1;
    f16x4 h;
    #pragma unroll
    for (int j = 0; j < 4; j++) h[j] = (_Float16)0.f;
    if (tt >= 0 && tt < TDIM && ff >= 0 && ff < FDIM) {
      float4 v = *reinterpret_cast<const float4*>(x + (((b * TDIM + tt) * FDIM + ff) << 6) + cq * 4);
      h[0] = (_Float16)v.x; h[1] = (_Float16)v.y; h[2] = (_Float16)v.z; h[3] = (_Float16)v.w;
    }
    *reinterpret_cast<f16x4*>(&xs[r2 * 72 + cq * 4]) = h;
  }
  __syncthreads();

  float bv = bias[c0 + lr];
  f32x4 acc[5];
  #pragma unroll
  for (int mt = 0; mt < 5; mt++)
    #pragma unroll
    for (int r = 0; r < 4; r++) acc[mt][r] = bv;

  for (int ky = 0; ky < 3; ky++) {
    f16x8 wf[3][2];
    #pragma unroll
    for (int kx = 0; kx < 3; kx++)
      #pragma unroll
      for (int cc = 0; cc < 2; cc++) {
        const float* wp = w + ((ky * 3 + kx) * 64 + cc * 32 + lg * 8) * 64 + c0 + lr;
        #pragma unroll
        for (int j = 0; j < 8; j++) wf[kx][cc][j] = (_Float16)wp[j * 64];
      }
    #pragma unroll
    for (int mt = 0; mt < 5; mt++) {
      #pragma unroll
      for (int kx = 0; kx < 3; kx++) {
        const _Float16* ap = &xs[(ky * 82 + mt * 16 + lr + kx) * 72];
        #pragma unroll
        for (int cc = 0; cc < 2; cc++) {
          f16x8 af = *reinterpret_cast<const f16x8*>(ap + cc * 32 + lg * 8);
          acc[mt] = __builtin_amdgcn_mfma_f32_16x16x32_f16(af, wf[kx][cc], acc[mt], 0, 0, 0);
        }
      }
    }
  }

  // epilogue: bounce [64 c][80 f] through LDS (alias xs), then coalesced f16x8 rows
  __syncthreads();                   // all waves done reading xs
  _Float16* yt = xs;                 // [64 c][88 f]
  const int c = c0 + lr;
  #pragma unroll
  for (int mt = 0; mt < 5; mt++) {
    f16x4 h;
    #pragma unroll
    for (int r = 0; r < 4; r++) h[r] = (_Float16)acc[mt][r];
    *reinterpret_cast<f16x4*>(&yt[c * 88 + mt * 16 + lg * 4]) = h;
  }
  __syncthreads();
  #pragma unroll
  for (int k = 0; k < 3; k++) {
    int idx = tid + (k << 8);
    if (idx < 640) {
      int cc = idx / 10, f8 = idx - cc * 10;
      *reinterpret_cast<f16x8*>(y + ((size_t)(b * 64 + cc) * TDIM + t) * FDIM + f8 * 8) =
          *reinterpret_cast<const f16x8*>(&yt[cc * 88 + f8 * 8]);
    }
  }
}

// ---------------- freq attention (MFMA, 8 waves, Q-tile 128, KVBLK=64, reg-prefetch) ----------------
// CAT2 layout: [B][128][T][F]; freq writes channels 64..127 (its own contiguous plane)
__global__ __launch_bounds__(512) void k_attn_freq(
    const _Float16* __restrict__ XQ, const _Float16* __restrict__ XK,
    const _Float16* __restrict__ XV, _Float16* __restrict__ CAT)
{
  __shared__ __align__(16) _Float16 Ks[64 * 104];   // [m][k], cols 80..103 pad (zeroed once)
  __shared__ __align__(16) _Float16 Vt[80 * 72];    // [f][m] transposed V, stride 72
  __shared__ __align__(16) _Float16 Pl[8 * 16 * 72];// per-wave P bounce [16 q][72], XOR-swizzled

  const int bid = blockIdx.x;                       // 2048 blocks
  // bijective remap: 8 bc x 4 tl co-resident per XCD chunk (1.3MB < L2)
  const int x8 = bid & 7, kk = bid >> 3;            // kk 0..255
  const int jj = kk & 7, tl = (kk >> 3) & 3, cc8 = kk >> 5;
  const int bc = x8 + cc8 * 64 + jj * 8;            // bc % 8 == x8 (XCD-stable)
  const int b = bc >> 6, c = bc & 63;
  const int t0 = tl * 128;
  const int tid = threadIdx.x;
  const int w8 = tid >> 6, ln = tid & 63;
  const int lr = ln & 15, lg = ln >> 4;
  const float qscale = 0.1118033988749895f;         // 1/sqrt(80)

  const _Float16* Qg = XQ + (size_t)bc * 40960 + (size_t)t0 * 80;
  const _Float16* Kg = XK + (size_t)bc * 40960;
  const _Float16* Vg = XV + (size_t)bc * 40960;

  // Q fragments direct from global (q-row = w8*16+lr; pad k=80..95 zero)
  f16x8 qf[3];
  qf[0] = *reinterpret_cast<const f16x8*>(Qg + (w8 * 16 + lr) * 80 + lg * 8);
  qf[1] = *reinterpret_cast<const f16x8*>(Qg + (w8 * 16 + lr) * 80 + 32 + lg * 8);
  {
    f16x8 z;
    #pragma unroll
    for (int j = 0; j < 8; j++) z[j] = (_Float16)0.f;
    qf[2] = (lg < 2) ? *reinterpret_cast<const f16x8*>(Qg + (w8 * 16 + lr) * 80 + 64 + lg * 8) : z;
  }

  if (tid < 192) {                                  // zero K pad cols 80..103 once
    int row = tid / 3, cw = tid - row * 3;
    f16x8 z;
    #pragma unroll
    for (int j = 0; j < 8; j++) z[j] = (_Float16)0.f;
    *reinterpret_cast<f16x8*>(&Ks[row * 104 + 80 + cw * 8]) = z;
  }

  // K tile = 640 f16x8 chunks: i = tid (512) + tid+512 (tid<128)
  // V tile: lane owns row vm = tid&63; 5 f16x2 chunks at f2 = w8 + 8s
  const int vm = tid & 63;
  f16x8 kreg0, kreg1;
  f16x2 vreg[5];
  {
    int i0 = tid, r0 = i0 / 10, w0 = i0 - r0 * 10;
    kreg0 = *reinterpret_cast<const f16x8*>(Kg + r0 * 80 + w0 * 8);
    if (tid < 128) {
      int i1 = tid + 512, r1 = i1 / 10, w1 = i1 - r1 * 10;
      kreg1 = *reinterpret_cast<const f16x8*>(Kg + r1 * 80 + w1 * 8);
    }
    #pragma unroll
    for (int s = 0; s < 5; s++)
      vreg[s] = *reinterpret_cast<const f16x2*>(Vg + vm * 80 + (w8 + 8 * s) * 2);
  }

  f32x4 O[5];
  #pragma unroll
  for (int ft = 0; ft < 5; ft++)
    #pragma unroll
    for (int r = 0; r < 4; r++) O[ft][r] = 0.f;
  float m_r[4], l_r[4];
  #pragma unroll
  for (int r = 0; r < 4; r++) { m_r[r] = -1e30f; l_r[r] = 0.f; }

  for (int kt = 0; kt < 8; kt++) {
    __syncthreads();                 // prior compute done reading LDS
    {
      int i0 = tid, r0 = i0 / 10, w0 = i0 - r0 * 10;
      *reinterpret_cast<f16x8*>(&Ks[r0 * 104 + w0 * 8]) = kreg0;
      if (tid < 128) {
        int i1 = tid + 512, r1 = i1 / 10, w1 = i1 - r1 * 10;
        *reinterpret_cast<f16x8*>(&Ks[r1 * 104 + w1 * 8]) = kreg1;
      }
      #pragma unroll
      for (int s = 0; s < 5; s++) {
        int f2 = (w8 + 8 * s) * 2;
        Vt[f2 * 72 + vm]       = vreg[s][0];
        Vt[(f2 + 1) * 72 + vm] = vreg[s][1];
      }
    }
    if (kt < 7) {
      const _Float16* Kn = Kg + (kt + 1) * 64 * 80;
      const _Float16* Vn = Vg + (kt + 1) * 64 * 80;
      int i0 = tid, r0 = i0 / 10, w0 = i0 - r0 * 10;
      kreg0 = *reinterpret_cast<const f16x8*>(Kn + r0 * 80 + w0 * 8);
      if (tid < 128) {
        int i1 = tid + 512, r1 = i1 / 10, w1 = i1 - r1 * 10;
        kreg1 = *reinterpret_cast<const f16x8*>(Kn + r1 * 80 + w1 * 8);
      }
      #pragma unroll
      for (int s = 0; s < 5; s++)
        vreg[s] = *reinterpret_cast<const f16x2*>(Vn + vm * 80 + (w8 + 8 * s) * 2);
    }
    __syncthreads();                 // LDS tile ready

    // ---- QK^T: S[16 q][64 m] per wave (12 MFMAs)
    f32x4 S[4];
    #pragma unroll
    for (int ms = 0; ms < 4; ms++)
      #pragma unroll
      for (int r = 0; r < 4; r++) S[ms][r] = 0.f;
    __builtin_amdgcn_s_setprio(1);
    #pragma unroll
    for (int kc = 0; kc < 3; kc++) {
      #pragma unroll
      for (int ms = 0; ms < 4; ms++) {
        f16x8 kf = *reinterpret_cast<const f16x8*>(&Ks[(ms * 16 + lr) * 104 + kc * 32 + lg * 8]);
        S[ms] = __builtin_amdgcn_mfma_f32_16x16x32_f16(qf[kc], kf, S[ms], 0, 0, 0);
      }
    }
    __builtin_amdgcn_s_setprio(0);

    // ---- online softmax (row q = lg*4+r, cols m = ms*16+lr)
    float p[4][4], corr[4];
    #pragma unroll
    for (int r = 0; r < 4; r++) {
      float s0 = S[0][r] * qscale, s1 = S[1][r] * qscale;
      float s2 = S[2][r] * qscale, s3 = S[3][r] * qscale;
      float tm = fmaxf(fmaxf(s0, s1), fmaxf(s2, s3));
      tm = fmaxf(tm, __shfl_xor(tm, 1, 16));
      tm = fmaxf(tm, __shfl_xor(tm, 2, 16));
      tm = fmaxf(tm, __shfl_xor(tm, 4, 16));
      tm = fmaxf(tm, __shfl_xor(tm, 8, 16));
      float mn = fmaxf(m_r[r], tm);
      corr[r] = __expf(m_r[r] - mn);
      m_r[r] = mn;
      p[0][r] = __expf(s0 - mn); p[1][r] = __expf(s1 - mn);
      p[2][r] = __expf(s2 - mn); p[3][r] = __expf(s3 - mn);
      float ls = (p[0][r] + p[1][r]) + (p[2][r] + p[3][r]);
      ls += __shfl_xor(ls, 1, 16);
      ls += __shfl_xor(ls, 2, 16);
      ls += __shfl_xor(ls, 4, 16);
      ls += __shfl_xor(ls, 8, 16);
      l_r[r] = l_r[r] * corr[r] + ls;
    }
    #pragma unroll
    for (int ft = 0; ft < 5; ft++)
      #pragma unroll
      for (int r = 0; r < 4; r++) O[ft][r] *= corr[r];

    // ---- P (C-layout) -> wave-private LDS (XOR-swizzled, conflict-free) -> A-layout frags
    _Float16* pw = &Pl[w8 * 16 * 72];
    #pragma unroll
    for (int r = 0; r < 4; r++) {
      int row = lg * 4 + r;
      #pragma unroll
      for (int ms = 0; ms < 4; ms++)
        pw[row * 72 + ((ms * 16 + lr) ^ (lg << 3))] = (_Float16)p[ms][r];
    }
    asm volatile("s_waitcnt lgkmcnt(0)" ::: "memory");
    const int sx = (lg ^ ((lr >> 2) & 3)) * 8;
    f16x8 pf0 = *reinterpret_cast<const f16x8*>(&pw[lr * 72 + sx]);
    f16x8 pf1 = *reinterpret_cast<const f16x8*>(&pw[lr * 72 + 32 + sx]);

    // ---- PV: O[16 q][80 f] += P(16x64) * V(64x80)  (10 MFMAs)
    __builtin_amdgcn_s_setprio(1);
    #pragma unroll
    for (int ft = 0; ft < 5; ft++) {
      f16x8 vf0 = *reinterpret_cast<const f16x8*>(&Vt[(ft * 16 + lr) * 72 + lg * 8]);
      f16x8 vf1 = *reinterpret_cast<const f16x8*>(&Vt[(ft * 16 + lr) * 72 + 32 + lg * 8]);
      O[ft] = __builtin_amdgcn_mfma_f32_16x16x32_f16(pf0, vf0, O[ft], 0, 0, 0);
      O[ft] = __builtin_amdgcn_mfma_f32_16x16x32_f16(pf1, vf1, O[ft], 0, 0, 0);
    }
    __builtin_amdgcn_s_setprio(0);
  }

  // epilogue: CAT2 [B][128][T][F], ch = 64+c: contiguous 16-half runs per (ft)
  #pragma unroll
  for (int r = 0; r < 4; r++) {
    float inv = 1.f / l_r[r];
    int t = t0 + w8 * 16 + lg * 4 + r;
    size_t base = ((size_t)(b * 128 + 64 + c) * TDIM + t) * FDIM;
    #pragma unroll
    for (int ft = 0; ft < 5; ft++)
      CAT[base + ft * 16 + lr] = (_Float16)(O[ft][r] * inv);
  }
}

// ---------------- time attention via MFMA: per (b,c); writes CAT2 channel c plane ----------------
__global__ __launch_bounds__(256) void k_attn_time(
    const _Float16* __restrict__ XQ, const _Float16* __restrict__ XK,
    const _Float16* __restrict__ XV, _Float16* __restrict__ CAT)
{
  __shared__ __align__(16) char smem[70400];
  _Float16* Qt  = (_Float16*)smem;              // [80][136] phase1
  _Float16* Kt  = Qt + 80 * 136;                // [80][136]
  float*    Sld = (float*)(smem + 43520);       // [80][84] fp32 scores
  _Float16* Pld = (_Float16*)smem;              // [80][104] phase2 (aliases Qt, post-barrier)

  const int bid = blockIdx.x;                   // 512 blocks = (b,c)
  const int b = bid >> 6, c = bid & 63;
  const int tid = threadIdx.x;
  const int wv = tid >> 6, ln = tid & 63;
  const int lr = ln & 15, lg = ln >> 4;
  const float tscale = 0.04419417382415922f;    // 1/sqrt(512)

  const _Float16* Qg = XQ + (size_t)bid * 40960;
  const _Float16* Kg = XK + (size_t)bid * 40960;
  const _Float16* Vg = XV + (size_t)bid * 40960;

  f32x4 sacc[7];
  #pragma unroll
  for (int i = 0; i < 7; i++)
    #pragma unroll
    for (int r = 0; r < 4; r++) sacc[i][r] = 0.f;

  for (int tc = 0; tc < 4; tc++) {
    __syncthreads();
    for (int idx = tid; idx < 640; idx += 256) {
      int t2 = idx / 10, f8 = idx - t2 * 10;
      int tg = tc * 128 + t2 * 2;
      f16x8 qa = *reinterpret_cast<const f16x8*>(Qg + (size_t)tg * 80 + f8 * 8);
      f16x8 qb = *reinterpret_cast<const f16x8*>(Qg + (size_t)(tg + 1) * 80 + f8 * 8);
      f16x8 ka = *reinterpret_cast<const f16x8*>(Kg + (size_t)tg * 80 + f8 * 8);
      f16x8 kb = *reinterpret_cast<const f16x8*>(Kg + (size_t)(tg + 1) * 80 + f8 * 8);
      #pragma unroll
      for (int j = 0; j < 8; j++) {
        int f = f8 * 8 + j;
        f16x2 qp; qp[0] = qa[j]; qp[1] = qb[j];
        f16x2 kp; kp[0] = ka[j]; kp[1] = kb[j];
        *reinterpret_cast<f16x2*>(&Qt[f * 136 + t2 * 2]) = qp;
        *reinterpret_cast<f16x2*>(&Kt[f * 136 + t2 * 2]) = kp;
      }
    }
    __syncthreads();
    #pragma unroll
    for (int i = 0; i < 7; i++) {
      int ti = wv * 7 + i;
      int te = ti < 25 ? ti : 24;
      int mi = te / 5, ni = te - mi * 5;
      #pragma unroll
      for (int kc = 0; kc < 4; kc++) {
        f16x8 aq = *reinterpret_cast<const f16x8*>(&Qt[(mi * 16 + lr) * 136 + kc * 32 + lg * 8]);
        f16x8 bk = *reinterpret_cast<const f16x8*>(&Kt[(ni * 16 + lr) * 136 + kc * 32 + lg * 8]);
        sacc[i] = __builtin_amdgcn_mfma_f32_16x16x32_f16(aq, bk, sacc[i], 0, 0, 0);
      }
    }
  }
  #pragma unroll
  for (int i = 0; i < 7; i++) {
    int ti = wv * 7 + i;
    if (ti < 25) {
      int mi = ti / 5, ni = ti - mi * 5;
      #pragma unroll
      for (int r = 0; r < 4; r++)
        Sld[(mi * 16 + lg * 4 + r) * 84 + ni * 16 + lr] = sacc[i][r] * tscale;
    }
  }
  __syncthreads();

  {
    const int fy = tid >> 4, gx = tid & 15;
    #pragma unroll
    for (int pass = 0; pass < 5; pass++) {
      int row = pass * 16 + fy;
      float s[5];
      #pragma unroll
      for (int j = 0; j < 5; j++) s[j] = Sld[row * 84 + gx + 16 * j];
      float mx = fmaxf(fmaxf(fmaxf(s[0], s[1]), fmaxf(s[2], s[3])), s[4]);
      #pragma unroll
      for (int sh = 1; sh < 16; sh <<= 1) mx = fmaxf(mx, __shfl_xor(mx, sh, 16));
      float e[5]; float ls = 0.f;
      #pragma unroll
      for (int j = 0; j < 5; j++) { e[j] = __expf(s[j] - mx); ls += e[j]; }
      #pragma unroll
      for (int sh = 1; sh < 16; sh <<= 1) ls += __shfl_xor(ls, sh, 16);
      float inv = 1.f / ls;
      #pragma unroll
      for (int j = 0; j < 5; j++)
        Pld[row * 104 + gx + 16 * j] = (_Float16)(e[j] * inv);
    }
    for (int idx = tid; idx < 240; idx += 256) {
      int row = idx / 3, cw = idx - row * 3;
      f16x8 z;
      #pragma unroll
      for (int j = 0; j < 8; j++) z[j] = (_Float16)0.f;
      *reinterpret_cast<f16x8*>(&Pld[row * 104 + 80 + cw * 8]) = z;
    }
  }
  __syncthreads();

  f16x8 pa[5][3];
  #pragma unroll
  for (int mi = 0; mi < 5; mi++)
    #pragma unroll
    for (int kc = 0; kc < 3; kc++)
      pa[mi][kc] = *reinterpret_cast<const f16x8*>(&Pld[(mi * 16 + lr) * 104 + kc * 32 + lg * 8]);

  _Float16* Ow = (_Float16*)(smem + 43520) + wv * (16 * 88);  // per-wave [16 t][88 f] (Sld dead)
  const size_t chbase = (size_t)(b * 128 + c) * TDIM * FDIM;

  #pragma unroll
  for (int j = 0; j < 8; j++) {
    int nt = wv * 8 + j;
    f16x8 vf[3];
    #pragma unroll
    for (int kc = 0; kc < 3; kc++) {
      if (kc < 2) {
        vf[kc] = *reinterpret_cast<const f16x8*>(Vg + (size_t)(nt * 16 + lr) * 80 + kc * 32 + lg * 8);
      } else {
        f16x8 z;
        #pragma unroll
        for (int q = 0; q < 8; q++) z[q] = (_Float16)0.f;
        vf[kc] = (lg < 2) ? *reinterpret_cast<const f16x8*>(Vg + (size_t)(nt * 16 + lr) * 80 + 64 + lg * 8) : z;
      }
    }
    f32x4 oacc[5];
    #pragma unroll
    for (int mi = 0; mi < 5; mi++)
      #pragma unroll
      for (int r = 0; r < 4; r++) oacc[mi][r] = 0.f;
    #pragma unroll
    for (int mi = 0; mi < 5; mi++)
      #pragma unroll
      for (int kc = 0; kc < 3; kc++)
        oacc[mi] = __builtin_amdgcn_mfma_f32_16x16x32_f16(pa[mi][kc], vf[kc], oacc[mi], 0, 0, 0);

    // transpose D-frag (t=nt*16+lr, f=mi*16+lg*4+r) through per-wave LDS, then coalesced rows
    #pragma unroll
    for (int mi = 0; mi < 5; mi++) {
      f16x4 h;
      #pragma unroll
      for (int r = 0; r < 4; r++) h[r] = (_Float16)oacc[mi][r];
      *reinterpret_cast<f16x4*>(&Ow[lr * 88 + mi * 16 + lg * 4]) = h;
    }
    asm volatile("s_waitcnt lgkmcnt(0)" ::: "memory");
    size_t basec = chbase + (size_t)(nt * 16) * FDIM;
    #pragma unroll
    for (int k = 0; k < 3; k++) {
      int idx = ln + (k << 6);
      if (idx < 160) {
        int tl2 = idx / 10, f8 = idx - tl2 * 10;
        *reinterpret_cast<f16x8*>(CAT + basec + tl2 * 80 + f8 * 8) =
            *reinterpret_cast<const f16x8*>(&Ow[tl2 * 88 + f8 * 8]);
      }
    }
  }
}

// ---------------- conv 3x3 128->64 via MFMA: in CAT2 [B][128][T][F] fp16, out NHWC [B,T,F,64] fp32 ----------------
__global__ __launch_bounds__(256) void k_conv_out(
    const _Float16* __restrict__ x, const float* __restrict__ w,
    const float* __restrict__ bias, float* __restrict__ out)
{
  __shared__ __align__(16) _Float16 xs[246 * 136];  // [ky*82+fi][ci], stride 136
  const int bid = blockIdx.x;
  const int b = bid >> 9, t = bid & 511;
  const int tid = threadIdx.x;
  const int wv = tid >> 6, ln = tid & 63;
  const int lr = ln & 15, lg = ln >> 4;
  const int c0 = wv * 16;

  // zero pad columns fi=0 and fi=81
  for (int idx = tid; idx < 768; idx += 256) {
    int cch = idx & 127, sk = idx >> 7;             // sk 0..5
    int ky = sk >> 1, side = sk & 1;
    xs[(ky * 82 + side * 81) * 136 + cch] = (_Float16)0.f;
  }
  // stage from channel-major CAT2: lanes span c (conflict-free LDS), reads via L2
  const _Float16* xb = x + (size_t)b * 128 * TDIM * FDIM;
  #pragma unroll
  for (int k = 0; k < 15; k++) {
    int idx = tid + (k << 8);                       // 0..3839
    int cch = idx & 127, rest = idx >> 7;           // rest 0..29
    int ky = rest / 10, f8 = rest - ky * 10;
    int tt = t + ky - 1;
    f16x8 h;
    #pragma unroll
    for (int j = 0; j < 8; j++) h[j] = (_Float16)0.f;
    if (tt >= 0 && tt < TDIM)
      h = *reinterpret_cast<const f16x8*>(xb + ((size_t)cch * TDIM + tt) * FDIM + f8 * 8);
    #pragma unroll
    for (int j = 0; j < 8; j++)
      xs[(ky * 82 + f8 * 8 + j + 1) * 136 + cch] = h[j];
  }
  __syncthreads();

  float bv = bias[c0 + lr];
  f32x4 acc[5];
  #pragma unroll
  for (int mt = 0; mt < 5; mt++)
    #pragma unroll
    for (int r = 0; r < 4; r++) acc[mt][r] = bv;

  for (int ky = 0; ky < 3; ky++) {
    f16x8 wf[3][4];
    #pragma unroll
    for (int kx = 0; kx < 3; kx++)
      #pragma unroll
      for (int cc = 0; cc < 4; cc++) {
        const float* wp = w + ((ky * 3 + kx) * 128 + cc * 32 + lg * 8) * 64 + c0 + lr;
        #pragma unroll
        for (int j = 0; j < 8; j++) wf[kx][cc][j] = (_Float16)wp[j * 64];
      }
    #pragma unroll
    for (int mt = 0; mt < 5; mt++) {
      #pragma unroll
      for (int kx = 0; kx < 3; kx++) {
        const _Float16* ap = &xs[(ky * 82 + mt * 16 + lr + kx) * 136];
        #pragma unroll
        for (int cc = 0; cc < 4; cc++) {
          f16x8 af = *reinterpret_cast<const f16x8*>(ap + cc * 32 + lg * 8);
          acc[mt] = __builtin_amdgcn_mfma_f32_16x16x32_f16(af, wf[kx][cc], acc[mt], 0, 0, 0);
        }
      }
    }
  }

  const int c = c0 + lr;
  #pragma unroll
  for (int mt = 0; mt < 5; mt++) {
    #pragma unroll
    for (int r = 0; r < 4; r++) {
      int f = mt * 16 + lg * 4 + r;
      out[((size_t)(b * TDIM + t) * FDIM + f) * 64 + c] = acc[mt][r];
    }
  }
}

extern "C" void kernel_launch(void* const* d_in, const int* in_sizes, int n_in,
                              void* d_out, int out_size, void* d_ws, size_t ws_size,
                              hipStream_t stream)
{
  const float* q  = (const float*)d_in[0];
  const float* k  = (const float*)d_in[1];
  const float* v  = (const float*)d_in[2];
  const float* wq = (const float*)d_in[3];
  const float* bq = (const float*)d_in[4];
  const float* wk = (const float*)d_in[5];
  const float* bk = (const float*)d_in[6];
  const float* wv = (const float*)d_in[7];
  const float* bv = (const float*)d_in[8];
  const float* wo = (const float*)d_in[9];
  const float* bo = (const float*)d_in[10];

  const size_t PLANE = (size_t)8 * 64 * 512 * 80;   // 20,971,520 elements
  _Float16* XQh  = (_Float16*)d_ws;
  _Float16* XKh  = XQh + PLANE;
  _Float16* CATh = XKh + PLANE;                     // CAT2 [B][128][T][F] fp16
  _Float16* XVh  = (_Float16*)d_out;                // dead before k_conv_out writes

  hipLaunchKernelGGL(k_conv_in, dim3(4096), dim3(256), 0, stream, q, wq, bq, XQh);
  hipLaunchKernelGGL(k_conv_in, dim3(4096), dim3(256), 0, stream, k, wk, bk, XKh);
  hipLaunchKernelGGL(k_conv_in, dim3(4096), dim3(256), 0, stream, v, wv, bv, XVh);
  hipLaunchKernelGGL(k_attn_freq, dim3(2048), dim3(512), 0, stream, XQh, XKh, XVh, CATh);
  hipLaunchKernelGGL(k_attn_time, dim3(512), dim3(256), 0, stream, XQh, XKh, XVh, CATh);
  hipLaunchKernelGGL(k_conv_out, dim3(4096), dim3(256), 0, stream, CATh, wo, bo, (float*)d_out);
}